// Round 1
// baseline (499.066 us; speedup 1.0000x reference)
//
#include <hip/hip_runtime.h>
#include <hip/hip_bf16.h>
#include <math.h>

#define B_ 4
#define L_ 512
#define V_ 4
#define D_ 256
#define DS_ 16
#define DI_ 512
#define DTR_ 16
#define ML (B_*L_)              /* 2048 rows per view */

/* workspace layout (floats) */
#define OFF_XLN  0
#define SZ_XLN   ((long)V_*ML*D_)          /* 2,097,152 */
#define OFF_XZ   (OFF_XLN + SZ_XLN)
#define SZ_XZ    ((long)V_*ML*2*DI_)       /* 8,388,608 */
#define OFF_XC   (OFF_XZ + SZ_XZ)
#define SZ_XC    ((long)V_*ML*DI_)         /* 4,194,304 */
#define OFF_XDBL (OFF_XC + SZ_XC)
#define SZ_XDBL  ((long)V_*ML*48)          /* 393,216  */

__device__ __forceinline__ float silu_f(float x) { return x / (1.f + expf(-x)); }

/* ---------------- LayerNorm: one block per (m, v) row, 256 threads = D ---------------- */
__global__ __launch_bounds__(256) void ln_kernel(const float* __restrict__ x,
                                                 const float* __restrict__ g,
                                                 const float* __restrict__ bta,
                                                 float* __restrict__ xln)
{
    const int m = blockIdx.x;           // 0..2047 (= b*L + l)
    const int v = blockIdx.y;
    const int d = threadIdx.x;
    const float val = x[((long)m*V_ + v)*D_ + d];
    float s = val, sq = val*val;
#pragma unroll
    for (int off = 32; off >= 1; off >>= 1) {
        s  += __shfl_xor(s, off);
        sq += __shfl_xor(sq, off);
    }
    __shared__ float ws[4], wq[4];
    if ((threadIdx.x & 63) == 0) { ws[threadIdx.x >> 6] = s; wq[threadIdx.x >> 6] = sq; }
    __syncthreads();
    s  = ws[0]+ws[1]+ws[2]+ws[3];
    sq = wq[0]+wq[1]+wq[2]+wq[3];
    const float mu  = s * (1.f/D_);
    const float var = sq * (1.f/D_) - mu*mu;
    const float inv = rsqrtf(var + 1e-5f);
    xln[((long)v*ML + m)*D_ + d] = (val - mu)*inv*g[v*D_+d] + bta[v*D_+d];
}

/* ---------------- generic fp32 NT GEMM: C[M,N] = A[M,K] * B[N,K]^T ----------------
   64x64 tile, 256 threads, 4x4 per thread, BK=16, LDS tiles stored k-major. */
__global__ __launch_bounds__(256) void gemm_nt64(const float* __restrict__ A,
                                                 const float* __restrict__ B,
                                                 float* __restrict__ C,
                                                 int K, int N,
                                                 long sAv, long sBv, long sCv)
{
    const int v = blockIdx.z;
    A += (long)v * sAv;  B += (long)v * sBv;  C += (long)v * sCv;
    __shared__ float As[16][68];
    __shared__ float Bs[16][68];
    const int tid = threadIdx.x;
    const int tx = tid & 15, ty = tid >> 4;
    const int bm = blockIdx.y * 64, bn = blockIdx.x * 64;
    const int lr = tid >> 2;            // 0..63 row-in-tile for loads
    const int lk = (tid & 3) * 4;       // k offset for loads
    const float* Ag = A + (long)(bm + lr)*K + lk;
    const float* Bg = B + (long)(bn + lr)*K + lk;
    float acc[4][4] = {};
    for (int k0 = 0; k0 < K; k0 += 16) {
        const float4 av = *(const float4*)(Ag + k0);
        const float4 bv = *(const float4*)(Bg + k0);
        __syncthreads();
        As[lk+0][lr]=av.x; As[lk+1][lr]=av.y; As[lk+2][lr]=av.z; As[lk+3][lr]=av.w;
        Bs[lk+0][lr]=bv.x; Bs[lk+1][lr]=bv.y; Bs[lk+2][lr]=bv.z; Bs[lk+3][lr]=bv.w;
        __syncthreads();
#pragma unroll
        for (int kk = 0; kk < 16; ++kk) {
            const float4 a = *(const float4*)&As[kk][ty*4];
            const float4 b = *(const float4*)&Bs[kk][tx*4];
            acc[0][0] = fmaf(a.x,b.x,acc[0][0]); acc[0][1] = fmaf(a.x,b.y,acc[0][1]);
            acc[0][2] = fmaf(a.x,b.z,acc[0][2]); acc[0][3] = fmaf(a.x,b.w,acc[0][3]);
            acc[1][0] = fmaf(a.y,b.x,acc[1][0]); acc[1][1] = fmaf(a.y,b.y,acc[1][1]);
            acc[1][2] = fmaf(a.y,b.z,acc[1][2]); acc[1][3] = fmaf(a.y,b.w,acc[1][3]);
            acc[2][0] = fmaf(a.z,b.x,acc[2][0]); acc[2][1] = fmaf(a.z,b.y,acc[2][1]);
            acc[2][2] = fmaf(a.z,b.z,acc[2][2]); acc[2][3] = fmaf(a.z,b.w,acc[2][3]);
            acc[3][0] = fmaf(a.w,b.x,acc[3][0]); acc[3][1] = fmaf(a.w,b.y,acc[3][1]);
            acc[3][2] = fmaf(a.w,b.z,acc[3][2]); acc[3][3] = fmaf(a.w,b.w,acc[3][3]);
        }
    }
#pragma unroll
    for (int i = 0; i < 4; ++i) {
        float4 r; r.x = acc[i][0]; r.y = acc[i][1]; r.z = acc[i][2]; r.w = acc[i][3];
        *(float4*)&C[(long)(bm + ty*4 + i)*N + bn + tx*4] = r;
    }
}

/* ---------------- GEMM variant for w_x: N=48 (BM=64, BN=48, TM=4, TN=3) ---------------- */
__global__ __launch_bounds__(256) void gemm_nt48(const float* __restrict__ A,
                                                 const float* __restrict__ B,
                                                 float* __restrict__ C,
                                                 int K, long sAv, long sBv, long sCv)
{
    const int v = blockIdx.z;
    A += (long)v * sAv;  B += (long)v * sBv;  C += (long)v * sCv;
    __shared__ float As[16][68];
    __shared__ float Bs[16][48];
    const int tid = threadIdx.x;
    const int tx = tid & 15, ty = tid >> 4;
    const int bm = blockIdx.y * 64;
    const int lr = tid >> 2;
    const int lk = (tid & 3) * 4;
    const float* Ag = A + (long)(bm + lr)*K + lk;
    float acc[4][3] = {};
    for (int k0 = 0; k0 < K; k0 += 16) {
        const float4 av = *(const float4*)(Ag + k0);
        float4 bv = {0,0,0,0};
        if (tid < 192) bv = *(const float4*)(B + (long)(tid >> 2)*K + k0 + (tid & 3)*4);
        __syncthreads();
        As[lk+0][lr]=av.x; As[lk+1][lr]=av.y; As[lk+2][lr]=av.z; As[lk+3][lr]=av.w;
        if (tid < 192) {
            const int br = tid >> 2, bk = (tid & 3)*4;
            Bs[bk+0][br]=bv.x; Bs[bk+1][br]=bv.y; Bs[bk+2][br]=bv.z; Bs[bk+3][br]=bv.w;
        }
        __syncthreads();
#pragma unroll
        for (int kk = 0; kk < 16; ++kk) {
            const float4 a = *(const float4*)&As[kk][ty*4];
            const float b0 = Bs[kk][tx*3+0], b1 = Bs[kk][tx*3+1], b2 = Bs[kk][tx*3+2];
            acc[0][0]=fmaf(a.x,b0,acc[0][0]); acc[0][1]=fmaf(a.x,b1,acc[0][1]); acc[0][2]=fmaf(a.x,b2,acc[0][2]);
            acc[1][0]=fmaf(a.y,b0,acc[1][0]); acc[1][1]=fmaf(a.y,b1,acc[1][1]); acc[1][2]=fmaf(a.y,b2,acc[1][2]);
            acc[2][0]=fmaf(a.z,b0,acc[2][0]); acc[2][1]=fmaf(a.z,b1,acc[2][1]); acc[2][2]=fmaf(a.z,b2,acc[2][2]);
            acc[3][0]=fmaf(a.w,b0,acc[3][0]); acc[3][1]=fmaf(a.w,b1,acc[3][1]); acc[3][2]=fmaf(a.w,b2,acc[3][2]);
        }
    }
#pragma unroll
    for (int i = 0; i < 4; ++i)
#pragma unroll
        for (int j = 0; j < 3; ++j)
            C[(long)(bm + ty*4 + i)*48 + tx*3 + j] = acc[i][j];
}

/* ---------------- depthwise causal conv (DCONV=4) + bias + SiLU ---------------- */
__global__ __launch_bounds__(512) void conv_silu(const float* __restrict__ xz,
                                                 const float* __restrict__ cw,
                                                 const float* __restrict__ cb,
                                                 float* __restrict__ xc)
{
    const int m = blockIdx.x;           // b*L + l
    const int v = blockIdx.y;
    const int c = threadIdx.x;          // 0..511
    const int l = m & 511;
    const float* xzv = xz + (long)v*ML*2*DI_;
    const float4 w4 = *(const float4*)&cw[((long)v*DI_ + c)*4];
    const float w[4] = {w4.x, w4.y, w4.z, w4.w};
    float acc = cb[v*DI_ + c];
#pragma unroll
    for (int k = 0; k < 4; ++k) {
        const int lp = l - 3 + k;
        if (lp >= 0) acc = fmaf(xzv[(long)(m - 3 + k)*(2*DI_) + c], w[k], acc);
    }
    xc[((long)v*ML + m)*DI_ + c] = silu_f(acc);
}

/* ---------------- delta = softplus(dt_lo @ w_dt^T + b_dt), stored into xz[:, :512] ---------------- */
__global__ __launch_bounds__(512) void delta_kernel(const float* __restrict__ xdbl,
                                                    const float* __restrict__ wdt,
                                                    const float* __restrict__ bdt,
                                                    float* __restrict__ xz)
{
    const int m = blockIdx.x;
    const int v = blockIdx.y;
    const int d = threadIdx.x;
    const float* xd = xdbl + ((long)v*ML + m)*48;
    const float* wr = wdt + ((long)v*DI_ + d)*DTR_;
    float acc = bdt[v*DI_ + d];
#pragma unroll
    for (int r = 0; r < 16; ++r) acc = fmaf(xd[r], wr[r], acc);
    const float sp = fmaxf(acc, 0.f) + log1pf(expf(-fabsf(acc)));
    xz[((long)v*ML + m)*(2*DI_) + d] = sp;
}

/* ---------------- fused selective scan + skip + gate; y written in-place over xc ----------------
   grid: 32 blocks = (v, b, d-chunk of 256); each thread owns one d with h[16] in registers. */
__global__ __launch_bounds__(256) void scan_kernel(const float* __restrict__ xz,
                                                   const float* __restrict__ xcin,
                                                   const float* __restrict__ xdbl,
                                                   const float* __restrict__ A_log,
                                                   const float* __restrict__ D_skip,
                                                   float* __restrict__ yout)
{
    const int bid = blockIdx.x;
    const int v  = bid >> 3;
    const int b  = (bid >> 1) & 3;
    const int ch = bid & 1;
    const int d  = ch*256 + threadIdx.x;
    const float* xzv = xz   + ((long)v*ML + (long)b*L_)*(2*DI_);
    const float* xcv = xcin + ((long)v*ML + (long)b*L_)*DI_;
    const float* xdv = xdbl + ((long)v*ML + (long)b*L_)*48;
    float*       yv  = yout + ((long)v*ML + (long)b*L_)*DI_;

    float a2[16];
#pragma unroll
    for (int n = 0; n < 16; ++n)
        a2[n] = -expf(A_log[((long)v*DI_ + d)*DS_ + n]) * 1.44269504088896341f;
    const float dsk = D_skip[v*DI_ + d];
    float h[16];
#pragma unroll
    for (int n = 0; n < 16; ++n) h[n] = 0.f;

    __shared__ float sBC[2][16][32];    /* [buf][step][Bc(16) | Cc(16)] */
    {
        const int i = threadIdx.x >> 5, j = threadIdx.x & 31;
        sBC[0][i]  [j] = xdv[(long)(i)   *48 + 16 + j];
        sBC[0][i+8][j] = xdv[(long)(i+8) *48 + 16 + j];
    }
    __syncthreads();

    for (int c = 0; c < 32; ++c) {      /* 32 chunks x 16 steps */
        float p0 = 0.f, p1 = 0.f;
        const int i = threadIdx.x >> 5, j = threadIdx.x & 31;
        if (c + 1 < 32) {
            p0 = xdv[(long)((c+1)*16 + i)   *48 + 16 + j];
            p1 = xdv[(long)((c+1)*16 + i+8) *48 + 16 + j];
        }
        /* batch-load this chunk's per-thread streams */
        float dl[16], xr[16], zr[16];
#pragma unroll
        for (int s = 0; s < 16; ++s) {
            const long m = (long)c*16 + s;
            dl[s] = xzv[m*(2*DI_) + d];
            zr[s] = xzv[m*(2*DI_) + DI_ + d];
            xr[s] = xcv[m*DI_ + d];
        }
        const int cb = c & 1;
#pragma unroll
        for (int s = 0; s < 16; ++s) {
            const float delta = dl[s], xcval = xr[s];
            const float t1 = delta * xcval;
            float ys = 0.f;
#pragma unroll
            for (int n = 0; n < 16; ++n) {
                const float e = exp2f(delta * a2[n]);
                h[n] = fmaf(e, h[n], t1 * sBC[cb][s][n]);
                ys   = fmaf(h[n], sBC[cb][s][16 + n], ys);
            }
            float outv = ys + xcval * dsk;
            outv *= silu_f(zr[s]);
            yv[((long)c*16 + s)*DI_ + d] = outv;
        }
        __syncthreads();
        if (c + 1 < 32) {
            sBC[(c+1)&1][i]  [j] = p0;
            sBC[(c+1)&1][i+8][j] = p1;
        }
        __syncthreads();
    }
}

/* ---------------- final GEMM + scatter into (B,L,V,D) output, duplicated (tuple) ---------------- */
__global__ __launch_bounds__(256) void gemm_out64(const float* __restrict__ A,
                                                  const float* __restrict__ B,
                                                  float* __restrict__ Cout)
{
    const int v = blockIdx.z;
    A += (long)v * ((long)ML*DI_);
    B += (long)v * ((long)D_*DI_);
    __shared__ float As[16][68];
    __shared__ float Bs[16][68];
    const int tid = threadIdx.x;
    const int tx = tid & 15, ty = tid >> 4;
    const int bm = blockIdx.y * 64, bn = blockIdx.x * 64;
    const int lr = tid >> 2;
    const int lk = (tid & 3) * 4;
    const int K = DI_;
    const float* Ag = A + (long)(bm + lr)*K + lk;
    const float* Bg = B + (long)(bn + lr)*K + lk;
    float acc[4][4] = {};
    for (int k0 = 0; k0 < K; k0 += 16) {
        const float4 av = *(const float4*)(Ag + k0);
        const float4 bv = *(const float4*)(Bg + k0);
        __syncthreads();
        As[lk+0][lr]=av.x; As[lk+1][lr]=av.y; As[lk+2][lr]=av.z; As[lk+3][lr]=av.w;
        Bs[lk+0][lr]=bv.x; Bs[lk+1][lr]=bv.y; Bs[lk+2][lr]=bv.z; Bs[lk+3][lr]=bv.w;
        __syncthreads();
#pragma unroll
        for (int kk = 0; kk < 16; ++kk) {
            const float4 a = *(const float4*)&As[kk][ty*4];
            const float4 b = *(const float4*)&Bs[kk][tx*4];
            acc[0][0] = fmaf(a.x,b.x,acc[0][0]); acc[0][1] = fmaf(a.x,b.y,acc[0][1]);
            acc[0][2] = fmaf(a.x,b.z,acc[0][2]); acc[0][3] = fmaf(a.x,b.w,acc[0][3]);
            acc[1][0] = fmaf(a.y,b.x,acc[1][0]); acc[1][1] = fmaf(a.y,b.y,acc[1][1]);
            acc[1][2] = fmaf(a.y,b.z,acc[1][2]); acc[1][3] = fmaf(a.y,b.w,acc[1][3]);
            acc[2][0] = fmaf(a.z,b.x,acc[2][0]); acc[2][1] = fmaf(a.z,b.y,acc[2][1]);
            acc[2][2] = fmaf(a.z,b.z,acc[2][2]); acc[2][3] = fmaf(a.z,b.w,acc[2][3]);
            acc[3][0] = fmaf(a.w,b.x,acc[3][0]); acc[3][1] = fmaf(a.w,b.y,acc[3][1]);
            acc[3][2] = fmaf(a.w,b.z,acc[3][2]); acc[3][3] = fmaf(a.w,b.w,acc[3][3]);
        }
    }
    const long TOT = (long)ML * V_ * D_;   /* 2,097,152 */
#pragma unroll
    for (int i = 0; i < 4; ++i) {
        const int m = bm + ty*4 + i;
        float4 r; r.x = acc[i][0]; r.y = acc[i][1]; r.z = acc[i][2]; r.w = acc[i][3];
        const long base = ((long)m*V_ + v)*D_ + bn + tx*4;
        *(float4*)&Cout[base]       = r;
        *(float4*)&Cout[base + TOT] = r;
    }
}

extern "C" void kernel_launch(void* const* d_in, const int* in_sizes, int n_in,
                              void* d_out, int out_size, void* d_ws, size_t ws_size,
                              hipStream_t stream)
{
    const float* x      = (const float*)d_in[0];
    const float* ln_g   = (const float*)d_in[1];
    const float* ln_b   = (const float*)d_in[2];
    const float* w_in   = (const float*)d_in[3];
    const float* conv_w = (const float*)d_in[4];
    const float* conv_b = (const float*)d_in[5];
    const float* w_x    = (const float*)d_in[6];
    const float* w_dt   = (const float*)d_in[7];
    const float* b_dt   = (const float*)d_in[8];
    const float* A_log  = (const float*)d_in[9];
    const float* D_skip = (const float*)d_in[10];
    const float* w_out  = (const float*)d_in[11];
    float* out = (float*)d_out;

    float* ws   = (float*)d_ws;
    float* xln  = ws + OFF_XLN;
    float* xz   = ws + OFF_XZ;
    float* xc   = ws + OFF_XC;
    float* xdbl = ws + OFF_XDBL;

    /* 1. LayerNorm -> xln (V, 2048, 256) */
    ln_kernel<<<dim3(ML, V_), 256, 0, stream>>>(x, ln_g, ln_b, xln);

    /* 2. xz = xln @ w_in^T : (2048,1024) per view */
    gemm_nt64<<<dim3((2*DI_)/64, ML/64, V_), 256, 0, stream>>>(
        xln, w_in, xz, D_, 2*DI_,
        (long)ML*D_, (long)(2*DI_)*D_, (long)ML*2*DI_);

    /* 3. depthwise causal conv + SiLU -> xc (V, 2048, 512) */
    conv_silu<<<dim3(ML, V_), DI_, 0, stream>>>(xz, conv_w, conv_b, xc);

    /* 4. xdbl = xc @ w_x^T : (2048, 48) per view */
    gemm_nt48<<<dim3(1, ML/64, V_), 256, 0, stream>>>(
        xc, w_x, xdbl, DI_,
        (long)ML*DI_, (long)48*DI_, (long)ML*48);

    /* 5. delta = softplus(xdbl[:, :16] @ w_dt^T + b_dt) -> stored into xz[:, :512] */
    delta_kernel<<<dim3(ML, V_), DI_, 0, stream>>>(xdbl, w_dt, b_dt, xz);

    /* 6. fused scan + skip + gate; y overwrites xc */
    scan_kernel<<<dim3(V_*B_*2), 256, 0, stream>>>(xz, xc, xdbl, A_log, D_skip, xc);

    /* 7. out = y @ w_out^T, scattered to (B,L,V,D), duplicated for the tuple */
    gemm_out64<<<dim3(D_/64, ML/64, V_), 256, 0, stream>>>(xc, w_out, out);
}

// Round 3
// 308.761 us; speedup vs baseline: 1.6163x; 1.6163x over previous
//
#include <hip/hip_runtime.h>
#include <hip/hip_bf16.h>
#include <math.h>

#define B_ 4
#define L_ 512
#define V_ 4
#define D_ 256
#define DS_ 16
#define DI_ 512
#define DTR_ 16
#define ML (B_*L_)              /* 2048 rows per view */
#define NC_ 16                  /* scan chunks */
#define CL_ 32                  /* steps per chunk = L_/NC_ */

/* workspace layout (floats) */
#define OFF_XLN  0
#define SZ_XLN   ((long)V_*ML*D_)          /* 2,097,152 — reused as HBUF after gemm_nt64 */
#define OFF_XZ   (OFF_XLN + SZ_XLN)
#define SZ_XZ    ((long)V_*ML*2*DI_)       /* 8,388,608 */
#define OFF_XC   (OFF_XZ + SZ_XZ)
#define SZ_XC    ((long)V_*ML*DI_)         /* 4,194,304 */
#define OFF_XDBL (OFF_XC + SZ_XC)
#define SZ_XDBL  ((long)V_*ML*48)          /* 393,216  */
#define OFF_SDEL (OFF_XDBL + SZ_XDBL)
#define SZ_SDEL  ((long)V_*B_*NC_*DI_)     /* 131,072  */

__device__ __forceinline__ float silu_f(float x) { return x / (1.f + expf(-x)); }

/* ---------------- LayerNorm: one block per (m, v) row, 256 threads = D ---------------- */
__global__ __launch_bounds__(256) void ln_kernel(const float* __restrict__ x,
                                                 const float* __restrict__ g,
                                                 const float* __restrict__ bta,
                                                 float* __restrict__ xln)
{
    const int m = blockIdx.x;           // 0..2047 (= b*L + l)
    const int v = blockIdx.y;
    const int d = threadIdx.x;
    const float val = x[((long)m*V_ + v)*D_ + d];
    float s = val, sq = val*val;
#pragma unroll
    for (int off = 32; off >= 1; off >>= 1) {
        s  += __shfl_xor(s, off);
        sq += __shfl_xor(sq, off);
    }
    __shared__ float ws[4], wq[4];
    if ((threadIdx.x & 63) == 0) { ws[threadIdx.x >> 6] = s; wq[threadIdx.x >> 6] = sq; }
    __syncthreads();
    s  = ws[0]+ws[1]+ws[2]+ws[3];
    sq = wq[0]+wq[1]+wq[2]+wq[3];
    const float mu  = s * (1.f/D_);
    const float var = sq * (1.f/D_) - mu*mu;
    const float inv = rsqrtf(var + 1e-5f);
    xln[((long)v*ML + m)*D_ + d] = (val - mu)*inv*g[v*D_+d] + bta[v*D_+d];
}

/* ---------------- generic fp32 NT GEMM: C[M,N] = A[M,K] * B[N,K]^T ----------------
   64x64 tile, 256 threads, 4x4 per thread, BK=16, LDS tiles stored k-major. */
__global__ __launch_bounds__(256) void gemm_nt64(const float* __restrict__ A,
                                                 const float* __restrict__ B,
                                                 float* __restrict__ C,
                                                 int K, int N,
                                                 long sAv, long sBv, long sCv)
{
    const int v = blockIdx.z;
    A += (long)v * sAv;  B += (long)v * sBv;  C += (long)v * sCv;
    __shared__ float As[16][68];
    __shared__ float Bs[16][68];
    const int tid = threadIdx.x;
    const int tx = tid & 15, ty = tid >> 4;
    const int bm = blockIdx.y * 64, bn = blockIdx.x * 64;
    const int lr = tid >> 2;            // 0..63 row-in-tile for loads
    const int lk = (tid & 3) * 4;       // k offset for loads
    const float* Ag = A + (long)(bm + lr)*K + lk;
    const float* Bg = B + (long)(bn + lr)*K + lk;
    float acc[4][4] = {};
    for (int k0 = 0; k0 < K; k0 += 16) {
        const float4 av = *(const float4*)(Ag + k0);
        const float4 bv = *(const float4*)(Bg + k0);
        __syncthreads();
        As[lk+0][lr]=av.x; As[lk+1][lr]=av.y; As[lk+2][lr]=av.z; As[lk+3][lr]=av.w;
        Bs[lk+0][lr]=bv.x; Bs[lk+1][lr]=bv.y; Bs[lk+2][lr]=bv.z; Bs[lk+3][lr]=bv.w;
        __syncthreads();
#pragma unroll
        for (int kk = 0; kk < 16; ++kk) {
            const float4 a = *(const float4*)&As[kk][ty*4];
            const float4 b = *(const float4*)&Bs[kk][tx*4];
            acc[0][0] = fmaf(a.x,b.x,acc[0][0]); acc[0][1] = fmaf(a.x,b.y,acc[0][1]);
            acc[0][2] = fmaf(a.x,b.z,acc[0][2]); acc[0][3] = fmaf(a.x,b.w,acc[0][3]);
            acc[1][0] = fmaf(a.y,b.x,acc[1][0]); acc[1][1] = fmaf(a.y,b.y,acc[1][1]);
            acc[1][2] = fmaf(a.y,b.z,acc[1][2]); acc[1][3] = fmaf(a.y,b.w,acc[1][3]);
            acc[2][0] = fmaf(a.z,b.x,acc[2][0]); acc[2][1] = fmaf(a.z,b.y,acc[2][1]);
            acc[2][2] = fmaf(a.z,b.z,acc[2][2]); acc[2][3] = fmaf(a.z,b.w,acc[2][3]);
            acc[3][0] = fmaf(a.w,b.x,acc[3][0]); acc[3][1] = fmaf(a.w,b.y,acc[3][1]);
            acc[3][2] = fmaf(a.w,b.z,acc[3][2]); acc[3][3] = fmaf(a.w,b.w,acc[3][3]);
        }
    }
#pragma unroll
    for (int i = 0; i < 4; ++i) {
        float4 r; r.x = acc[i][0]; r.y = acc[i][1]; r.z = acc[i][2]; r.w = acc[i][3];
        *(float4*)&C[(long)(bm + ty*4 + i)*N + bn + tx*4] = r;
    }
}

/* ---------------- GEMM variant for w_x: N=48 (BM=64, BN=48, TM=4, TN=3) ---------------- */
__global__ __launch_bounds__(256) void gemm_nt48(const float* __restrict__ A,
                                                 const float* __restrict__ B,
                                                 float* __restrict__ C,
                                                 int K, long sAv, long sBv, long sCv)
{
    const int v = blockIdx.z;
    A += (long)v * sAv;  B += (long)v * sBv;  C += (long)v * sCv;
    __shared__ float As[16][68];
    __shared__ float Bs[16][48];
    const int tid = threadIdx.x;
    const int tx = tid & 15, ty = tid >> 4;
    const int bm = blockIdx.y * 64;
    const int lr = tid >> 2;
    const int lk = (tid & 3) * 4;
    const float* Ag = A + (long)(bm + lr)*K + lk;
    float acc[4][3] = {};
    for (int k0 = 0; k0 < K; k0 += 16) {
        const float4 av = *(const float4*)(Ag + k0);
        float4 bv = {0,0,0,0};
        if (tid < 192) bv = *(const float4*)(B + (long)(tid >> 2)*K + k0 + (tid & 3)*4);
        __syncthreads();
        As[lk+0][lr]=av.x; As[lk+1][lr]=av.y; As[lk+2][lr]=av.z; As[lk+3][lr]=av.w;
        if (tid < 192) {
            const int br = tid >> 2, bk = (tid & 3)*4;
            Bs[bk+0][br]=bv.x; Bs[bk+1][br]=bv.y; Bs[bk+2][br]=bv.z; Bs[bk+3][br]=bv.w;
        }
        __syncthreads();
#pragma unroll
        for (int kk = 0; kk < 16; ++kk) {
            const float4 a = *(const float4*)&As[kk][ty*4];
            const float b0 = Bs[kk][tx*3+0], b1 = Bs[kk][tx*3+1], b2 = Bs[kk][tx*3+2];
            acc[0][0]=fmaf(a.x,b0,acc[0][0]); acc[0][1]=fmaf(a.x,b1,acc[0][1]); acc[0][2]=fmaf(a.x,b2,acc[0][2]);
            acc[1][0]=fmaf(a.y,b0,acc[1][0]); acc[1][1]=fmaf(a.y,b1,acc[1][1]); acc[1][2]=fmaf(a.y,b2,acc[1][2]);
            acc[2][0]=fmaf(a.z,b0,acc[2][0]); acc[2][1]=fmaf(a.z,b1,acc[2][1]); acc[2][2]=fmaf(a.z,b2,acc[2][2]);
            acc[3][0]=fmaf(a.w,b0,acc[3][0]); acc[3][1]=fmaf(a.w,b1,acc[3][1]); acc[3][2]=fmaf(a.w,b2,acc[3][2]);
        }
    }
#pragma unroll
    for (int i = 0; i < 4; ++i)
#pragma unroll
        for (int j = 0; j < 3; ++j)
            C[(long)(bm + ty*4 + i)*48 + tx*3 + j] = acc[i][j];
}

/* ---------------- depthwise causal conv (DCONV=4) + bias + SiLU ---------------- */
__global__ __launch_bounds__(512) void conv_silu(const float* __restrict__ xz,
                                                 const float* __restrict__ cw,
                                                 const float* __restrict__ cb,
                                                 float* __restrict__ xc)
{
    const int m = blockIdx.x;           // b*L + l
    const int v = blockIdx.y;
    const int c = threadIdx.x;          // 0..511
    const int l = m & 511;
    const float* xzv = xz + (long)v*ML*2*DI_;
    const float4 w4 = *(const float4*)&cw[((long)v*DI_ + c)*4];
    const float w[4] = {w4.x, w4.y, w4.z, w4.w};
    float acc = cb[v*DI_ + c];
#pragma unroll
    for (int k = 0; k < 4; ++k) {
        const int lp = l - 3 + k;
        if (lp >= 0) acc = fmaf(xzv[(long)(m - 3 + k)*(2*DI_) + c], w[k], acc);
    }
    xc[((long)v*ML + m)*DI_ + c] = silu_f(acc);
}

/* ---------------- delta = softplus(dt_lo @ w_dt^T + b_dt), stored into xz[:, :512] ---------------- */
__global__ __launch_bounds__(512) void delta_kernel(const float* __restrict__ xdbl,
                                                    const float* __restrict__ wdt,
                                                    const float* __restrict__ bdt,
                                                    float* __restrict__ xz)
{
    const int m = blockIdx.x;
    const int v = blockIdx.y;
    const int d = threadIdx.x;
    const float* xd = xdbl + ((long)v*ML + m)*48;
    const float* wr = wdt + ((long)v*DI_ + d)*DTR_;
    float acc = bdt[v*DI_ + d];
#pragma unroll
    for (int r = 0; r < 16; ++r) acc = fmaf(xd[r], wr[r], acc);
    const float sp = fmaxf(acc, 0.f) + log1pf(expf(-fabsf(acc)));
    xz[((long)v*ML + m)*(2*DI_) + d] = sp;
}

/* ================= chunked parallel scan =================
   Recurrence h = exp(delta*A)*h + delta*B*xc is LINEAR in h.
   Phase A: per chunk c (CL_ steps), local scan with h0=0 -> h_end, plus S_delta = sum(delta).
            (decay product collapses: prod exp2(a2*delta_i) = exp2(a2*S_delta))
   Phase B: per (v,b,d,n): serial combine over NC_ chunks, in-place h_end -> h_in.
   Phase C: re-run local scan seeded with h_in, emit y = C.h + xc*Dskip, gated by silu(z). */

__global__ __launch_bounds__(256) void scanA(const float* __restrict__ xz,
                                             const float* __restrict__ xcin,
                                             const float* __restrict__ xdbl,
                                             const float* __restrict__ A_log,
                                             float* __restrict__ hbuf,
                                             float* __restrict__ sdel)
{
    const int c = blockIdx.x >> 1, half = blockIdx.x & 1;
    const int b = blockIdx.y, v = blockIdx.z;
    const int d = half*256 + threadIdx.x;
    const long rowbase = (long)v*ML + (long)b*L_ + (long)c*CL_;
    const float* xzv = xz   + rowbase*(2*DI_);
    const float* xcv = xcin + rowbase*DI_;
    const float* xdv = xdbl + rowbase*48;

    __shared__ float sB[CL_][16];
    {
        int t = threadIdx.x;
        sB[t>>4][t&15] = xdv[(long)(t>>4)*48 + 16 + (t&15)];
        t += 256;
        sB[t>>4][t&15] = xdv[(long)(t>>4)*48 + 16 + (t&15)];
    }
    float a2[16];
#pragma unroll
    for (int n = 0; n < 16; ++n)
        a2[n] = -expf(A_log[((long)v*DI_ + d)*DS_ + n]) * 1.44269504088896341f;
    float h[16];
#pragma unroll
    for (int n = 0; n < 16; ++n) h[n] = 0.f;
    float sd = 0.f;
    __syncthreads();

    for (int g = 0; g < CL_; g += 8) {
        float dl[8], xr[8];
#pragma unroll
        for (int s = 0; s < 8; ++s) {
            dl[s] = xzv[(long)(g+s)*(2*DI_) + d];
            xr[s] = xcv[(long)(g+s)*DI_ + d];
        }
#pragma unroll
        for (int s = 0; s < 8; ++s) {
            const float delta = dl[s];
            const float t1 = delta * xr[s];
            sd += delta;
#pragma unroll
            for (int n = 0; n < 16; ++n)
                h[n] = fmaf(exp2f(delta*a2[n]), h[n], t1*sB[g+s][n]);
        }
    }
    float* hb = hbuf + ((((long)v*B_ + b)*NC_ + c)*DI_ + d)*16;
#pragma unroll
    for (int n = 0; n < 16; n += 4) {
        float4 r; r.x = h[n]; r.y = h[n+1]; r.z = h[n+2]; r.w = h[n+3];
        *(float4*)&hb[n] = r;
    }
    sdel[(((long)v*B_ + b)*NC_ + c)*DI_ + d] = sd;
}

__global__ __launch_bounds__(256) void scanB(const float* __restrict__ A_log,
                                             const float* __restrict__ sdel,
                                             float* __restrict__ hbuf)
{
    const long lin = (long)blockIdx.x*256 + threadIdx.x;   /* 131072 = V*B*DI*DS */
    const int n = (int)(lin & 15);
    const int d = (int)((lin >> 4) & 511);
    const int b = (int)((lin >> 13) & 3);
    const int v = (int)(lin >> 15);
    const float a2 = -expf(A_log[((long)v*DI_ + d)*DS_ + n]) * 1.44269504088896341f;
    float h = 0.f;
    long hidx = ((long)(v*B_ + b)*NC_)*DI_*16 + (long)d*16 + n;
    long sidx = ((long)(v*B_ + b)*NC_)*DI_ + d;
#pragma unroll
    for (int c = 0; c < NC_; ++c) {
        const float he = hbuf[hidx];
        const float P  = exp2f(a2 * sdel[sidx]);
        hbuf[hidx] = h;                 /* incoming state for chunk c */
        h = fmaf(P, h, he);
        hidx += (long)DI_*16;
        sidx += DI_;
    }
}

__global__ __launch_bounds__(256) void scanC(const float* __restrict__ xz,
                                             const float* __restrict__ xcin,
                                             const float* __restrict__ xdbl,
                                             const float* __restrict__ A_log,
                                             const float* __restrict__ D_skip,
                                             const float* __restrict__ hbuf,
                                             float* __restrict__ yout)
{
    const int c = blockIdx.x >> 1, half = blockIdx.x & 1;
    const int b = blockIdx.y, v = blockIdx.z;
    const int d = half*256 + threadIdx.x;
    const long rowbase = (long)v*ML + (long)b*L_ + (long)c*CL_;
    const float* xzv = xz   + rowbase*(2*DI_);
    const float* xcv = xcin + rowbase*DI_;
    const float* xdv = xdbl + rowbase*48;
    float*       yv  = yout + rowbase*DI_;

    __shared__ float sBC[CL_][32];
    for (int t = threadIdx.x; t < CL_*32; t += 256)
        sBC[t>>5][t&31] = xdv[(long)(t>>5)*48 + 16 + (t&31)];

    float a2[16];
#pragma unroll
    for (int n = 0; n < 16; ++n)
        a2[n] = -expf(A_log[((long)v*DI_ + d)*DS_ + n]) * 1.44269504088896341f;
    const float dsk = D_skip[v*DI_ + d];
    float h[16];
    const float* hb = hbuf + ((((long)v*B_ + b)*NC_ + c)*DI_ + d)*16;
#pragma unroll
    for (int n = 0; n < 16; n += 4) {
        const float4 r = *(const float4*)&hb[n];
        h[n] = r.x; h[n+1] = r.y; h[n+2] = r.z; h[n+3] = r.w;
    }
    __syncthreads();

    for (int g = 0; g < CL_; g += 8) {
        float dl[8], xr[8], zr[8];
#pragma unroll
        for (int s = 0; s < 8; ++s) {
            dl[s] = xzv[(long)(g+s)*(2*DI_) + d];
            zr[s] = xzv[(long)(g+s)*(2*DI_) + DI_ + d];
            xr[s] = xcv[(long)(g+s)*DI_ + d];
        }
#pragma unroll
        for (int s = 0; s < 8; ++s) {
            const float delta = dl[s], xcval = xr[s];
            const float t1 = delta * xcval;
            float ys = 0.f;
#pragma unroll
            for (int n = 0; n < 16; ++n) {
                const float e = exp2f(delta*a2[n]);
                h[n] = fmaf(e, h[n], t1*sBC[g+s][n]);
                ys   = fmaf(h[n], sBC[g+s][16+n], ys);
            }
            float outv = ys + xcval * dsk;
            outv *= silu_f(zr[s]);
            yv[(long)(g+s)*DI_ + d] = outv;
        }
    }
}

/* ---------------- final GEMM + scatter into (B,L,V,D) output, duplicated (tuple) ---------------- */
__global__ __launch_bounds__(256) void gemm_out64(const float* __restrict__ A,
                                                  const float* __restrict__ B,
                                                  float* __restrict__ Cout)
{
    const int v = blockIdx.z;
    A += (long)v * ((long)ML*DI_);
    B += (long)v * ((long)D_*DI_);
    __shared__ float As[16][68];
    __shared__ float Bs[16][68];
    const int tid = threadIdx.x;
    const int tx = tid & 15, ty = tid >> 4;
    const int bm = blockIdx.y * 64, bn = blockIdx.x * 64;
    const int lr = tid >> 2;
    const int lk = (tid & 3) * 4;
    const int K = DI_;
    const float* Ag = A + (long)(bm + lr)*K + lk;
    const float* Bg = B + (long)(bn + lr)*K + lk;
    float acc[4][4] = {};
    for (int k0 = 0; k0 < K; k0 += 16) {
        const float4 av = *(const float4*)(Ag + k0);
        const float4 bv = *(const float4*)(Bg + k0);
        __syncthreads();
        As[lk+0][lr]=av.x; As[lk+1][lr]=av.y; As[lk+2][lr]=av.z; As[lk+3][lr]=av.w;
        Bs[lk+0][lr]=bv.x; Bs[lk+1][lr]=bv.y; Bs[lk+2][lr]=bv.z; Bs[lk+3][lr]=bv.w;
        __syncthreads();
#pragma unroll
        for (int kk = 0; kk < 16; ++kk) {
            const float4 a = *(const float4*)&As[kk][ty*4];
            const float4 b = *(const float4*)&Bs[kk][tx*4];
            acc[0][0] = fmaf(a.x,b.x,acc[0][0]); acc[0][1] = fmaf(a.x,b.y,acc[0][1]);
            acc[0][2] = fmaf(a.x,b.z,acc[0][2]); acc[0][3] = fmaf(a.x,b.w,acc[0][3]);
            acc[1][0] = fmaf(a.y,b.x,acc[1][0]); acc[1][1] = fmaf(a.y,b.y,acc[1][1]);
            acc[1][2] = fmaf(a.y,b.z,acc[1][2]); acc[1][3] = fmaf(a.y,b.w,acc[1][3]);
            acc[2][0] = fmaf(a.z,b.x,acc[2][0]); acc[2][1] = fmaf(a.z,b.y,acc[2][1]);
            acc[2][2] = fmaf(a.z,b.z,acc[2][2]); acc[2][3] = fmaf(a.z,b.w,acc[2][3]);
            acc[3][0] = fmaf(a.w,b.x,acc[3][0]); acc[3][1] = fmaf(a.w,b.y,acc[3][1]);
            acc[3][2] = fmaf(a.w,b.z,acc[3][2]); acc[3][3] = fmaf(a.w,b.w,acc[3][3]);
        }
    }
    const long TOT = (long)ML * V_ * D_;   /* 2,097,152 */
#pragma unroll
    for (int i = 0; i < 4; ++i) {
        const int m = bm + ty*4 + i;
        float4 r; r.x = acc[i][0]; r.y = acc[i][1]; r.z = acc[i][2]; r.w = acc[i][3];
        const long base = ((long)m*V_ + v)*D_ + bn + tx*4;
        *(float4*)&Cout[base]       = r;
        *(float4*)&Cout[base + TOT] = r;
    }
}

extern "C" void kernel_launch(void* const* d_in, const int* in_sizes, int n_in,
                              void* d_out, int out_size, void* d_ws, size_t ws_size,
                              hipStream_t stream)
{
    const float* x      = (const float*)d_in[0];
    const float* ln_g   = (const float*)d_in[1];
    const float* ln_b   = (const float*)d_in[2];
    const float* w_in   = (const float*)d_in[3];
    const float* conv_w = (const float*)d_in[4];
    const float* conv_b = (const float*)d_in[5];
    const float* w_x    = (const float*)d_in[6];
    const float* w_dt   = (const float*)d_in[7];
    const float* b_dt   = (const float*)d_in[8];
    const float* A_log  = (const float*)d_in[9];
    const float* D_skip = (const float*)d_in[10];
    const float* w_out  = (const float*)d_in[11];
    float* out = (float*)d_out;

    float* ws   = (float*)d_ws;
    float* xln  = ws + OFF_XLN;     /* reused as hbuf after gemm_nt64 */
    float* xz   = ws + OFF_XZ;
    float* xc   = ws + OFF_XC;
    float* xdbl = ws + OFF_XDBL;
    float* sdel = ws + OFF_SDEL;
    float* hbuf = xln;

    /* 1. LayerNorm -> xln (V, 2048, 256) */
    ln_kernel<<<dim3(ML, V_), 256, 0, stream>>>(x, ln_g, ln_b, xln);

    /* 2. xz = xln @ w_in^T : (2048,1024) per view */
    gemm_nt64<<<dim3((2*DI_)/64, ML/64, V_), 256, 0, stream>>>(
        xln, w_in, xz, D_, 2*DI_,
        (long)ML*D_, (long)(2*DI_)*D_, (long)ML*2*DI_);

    /* 3. depthwise causal conv + SiLU -> xc (V, 2048, 512) */
    conv_silu<<<dim3(ML, V_), DI_, 0, stream>>>(xz, conv_w, conv_b, xc);

    /* 4. xdbl = xc @ w_x^T : (2048, 48) per view */
    gemm_nt48<<<dim3(1, ML/64, V_), 256, 0, stream>>>(
        xc, w_x, xdbl, DI_,
        (long)ML*DI_, (long)48*DI_, (long)ML*48);

    /* 5. delta = softplus(xdbl[:, :16] @ w_dt^T + b_dt) -> stored into xz[:, :512] */
    delta_kernel<<<dim3(ML, V_), DI_, 0, stream>>>(xdbl, w_dt, b_dt, xz);

    /* 6. chunked parallel scan: A (local) -> B (combine) -> C (seeded + epilogue) */
    scanA<<<dim3(NC_*2, B_, V_), 256, 0, stream>>>(xz, xc, xdbl, A_log, hbuf, sdel);
    scanB<<<dim3((V_*B_*DI_*DS_)/256), 256, 0, stream>>>(A_log, sdel, hbuf);
    scanC<<<dim3(NC_*2, B_, V_), 256, 0, stream>>>(xz, xc, xdbl, A_log, D_skip, hbuf, xc);

    /* 7. out = y @ w_out^T, scattered to (B,L,V,D), duplicated for the tuple */
    gemm_out64<<<dim3(D_/64, ML/64, V_), 256, 0, stream>>>(xc, w_out, out);
}

// Round 4
// 271.428 us; speedup vs baseline: 1.8387x; 1.1375x over previous
//
#include <hip/hip_runtime.h>
#include <hip/hip_bf16.h>
#include <math.h>

#define B_ 4
#define L_ 512
#define V_ 4
#define D_ 256
#define DS_ 16
#define DI_ 512
#define DTR_ 16
#define ML (B_*L_)              /* 2048 rows per view */
#define NC_ 16                  /* scan chunks */
#define CL_ 32                  /* steps per chunk = L_/NC_ */

/* workspace layout (floats)
   REGION RA: xln hi/lo (pre-gemm_in) -> hbuf (scan) -> w_out hi/lo (post-scanC)
   REGION XC: w_in hi/lo (pre-gemm_in) -> xc f32 (conv..scanC) -> packed y (scanC, in-place) */
#define OFF_RA   0
#define SZ_RA    ((long)V_*ML*D_)          /* 2,097,152 floats */
#define OFF_XZ   (OFF_RA + SZ_RA)
#define SZ_XZ    ((long)V_*ML*2*DI_)       /* 8,388,608 */
#define OFF_XC   (OFF_XZ + SZ_XZ)
#define SZ_XC    ((long)V_*ML*DI_)         /* 4,194,304 */
#define OFF_XDBL (OFF_XC + SZ_XC)
#define SZ_XDBL  ((long)V_*ML*48)
#define OFF_SDEL (OFF_XDBL + SZ_XDBL)
#define SZ_SDEL  ((long)V_*B_*NC_*DI_)

typedef short short8_t __attribute__((ext_vector_type(8)));
typedef float f32x4_t  __attribute__((ext_vector_type(4)));

__device__ __forceinline__ float silu_f(float x) { return x / (1.f + expf(-x)); }
/* f32 -> bf16 round-to-nearest-even */
__device__ __forceinline__ ushort f2bf(float f) {
    uint u = __float_as_uint(f);
    return (ushort)((u + 0x7fffu + ((u >> 16) & 1u)) >> 16);
}
__device__ __forceinline__ float bf2f(ushort h) { return __uint_as_float(((uint)h) << 16); }

/* ---------------- weight hi/lo split (vectorized float4) ---------------- */
__global__ __launch_bounds__(256) void split_w(const float* __restrict__ in,
                                               ushort* __restrict__ oh,
                                               ushort* __restrict__ ol, int n4)
{
    const int i = blockIdx.x*256 + threadIdx.x;
    if (i >= n4) return;
    const float4 f = ((const float4*)in)[i];
    const ushort h0=f2bf(f.x), h1=f2bf(f.y), h2=f2bf(f.z), h3=f2bf(f.w);
    ((short4*)oh)[i] = make_short4((short)h0,(short)h1,(short)h2,(short)h3);
    ((short4*)ol)[i] = make_short4((short)f2bf(f.x-bf2f(h0)), (short)f2bf(f.y-bf2f(h1)),
                                   (short)f2bf(f.z-bf2f(h2)), (short)f2bf(f.w-bf2f(h3)));
}

/* ---------------- LayerNorm fused with hi/lo split ---------------- */
__global__ __launch_bounds__(256) void ln_split(const float* __restrict__ x,
                                                const float* __restrict__ g,
                                                const float* __restrict__ bta,
                                                ushort* __restrict__ xh,
                                                ushort* __restrict__ xl)
{
    const int m = blockIdx.x;
    const int v = blockIdx.y;
    const int d = threadIdx.x;
    const float val = x[((long)m*V_ + v)*D_ + d];
    float s = val, sq = val*val;
#pragma unroll
    for (int off = 32; off >= 1; off >>= 1) {
        s  += __shfl_xor(s, off);
        sq += __shfl_xor(sq, off);
    }
    __shared__ float ws[4], wq[4];
    if ((threadIdx.x & 63) == 0) { ws[threadIdx.x >> 6] = s; wq[threadIdx.x >> 6] = sq; }
    __syncthreads();
    s  = ws[0]+ws[1]+ws[2]+ws[3];
    sq = wq[0]+wq[1]+wq[2]+wq[3];
    const float mu  = s * (1.f/D_);
    const float var = sq * (1.f/D_) - mu*mu;
    const float inv = rsqrtf(var + 1e-5f);
    const float r = (val - mu)*inv*g[v*D_+d] + bta[v*D_+d];
    const ushort h = f2bf(r);
    const long idx = ((long)v*ML + m)*D_ + d;
    xh[idx] = h;
    xl[idx] = f2bf(r - bf2f(h));
}

/* ---------------- split-bf16 MFMA GEMM (in): xz[M=2048,N=1024] = A[M,K=256] @ B[N,K]^T
   C = Ah*Bh + Ah*Bl + Al*Bh (3-term fp32 emulation). 128x128 tile, 4 waves (2x2),
   wave tile 64x64 = 4x4 frags of 16x16x32. LDS rows padded to 40 ushorts. ---------------- */
__global__ __launch_bounds__(256,2) void mfma_gemm_in(
    const ushort* __restrict__ Ah, const ushort* __restrict__ Al,
    const ushort* __restrict__ Bh, const ushort* __restrict__ Bl,
    float* __restrict__ C)
{
    const int v = blockIdx.z;
    const long Ao = (long)v*ML*D_;
    const long Bo = (long)v*(2*DI_)*D_;
    C += (long)v*ML*(2*DI_);
    const int bm = blockIdx.y*128, bn = blockIdx.x*128;
    __shared__ ushort sAh[128][40], sAl[128][40], sBh[128][40], sBl[128][40];
    const int tid  = threadIdx.x;
    const int lane = tid & 63, w = tid >> 6;
    const int wr = w >> 1, wc = w & 1;
    const int fm = lane & 15, fg = lane >> 4;
    const int r = tid >> 1, q0 = (tid & 1)*2;          /* staging: row r, chunks q0,q0+1 */

    f32x4_t acc[4][4];
#pragma unroll
    for (int i=0;i<4;++i)
#pragma unroll
        for (int j=0;j<4;++j)
#pragma unroll
            for (int k=0;k<4;++k) acc[i][j][k]=0.f;

    const ushort* Agh = Ah + Ao + (long)(bm+r)*D_ + q0*8;
    const ushort* Agl = Al + Ao + (long)(bm+r)*D_ + q0*8;
    const ushort* Bgh = Bh + Bo + (long)(bn+r)*D_ + q0*8;
    const ushort* Bgl = Bl + Bo + (long)(bn+r)*D_ + q0*8;

    for (int k0 = 0; k0 < D_; k0 += 32) {
        const uint4 a0 = *(const uint4*)(Agh + k0);
        const uint4 a1 = *(const uint4*)(Agh + k0 + 8);
        const uint4 a2 = *(const uint4*)(Agl + k0);
        const uint4 a3 = *(const uint4*)(Agl + k0 + 8);
        const uint4 b0 = *(const uint4*)(Bgh + k0);
        const uint4 b1 = *(const uint4*)(Bgh + k0 + 8);
        const uint4 b2 = *(const uint4*)(Bgl + k0);
        const uint4 b3 = *(const uint4*)(Bgl + k0 + 8);
        __syncthreads();
        *(uint4*)&sAh[r][q0*8]   = a0;  *(uint4*)&sAh[r][q0*8+8] = a1;
        *(uint4*)&sAl[r][q0*8]   = a2;  *(uint4*)&sAl[r][q0*8+8] = a3;
        *(uint4*)&sBh[r][q0*8]   = b0;  *(uint4*)&sBh[r][q0*8+8] = b1;
        *(uint4*)&sBl[r][q0*8]   = b2;  *(uint4*)&sBl[r][q0*8+8] = b3;
        __syncthreads();
        short8_t ah[4], al[4], bh[4], bl[4];
#pragma unroll
        for (int i=0;i<4;++i) {
            ah[i] = *(const short8_t*)&sAh[wr*64 + i*16 + fm][fg*8];
            al[i] = *(const short8_t*)&sAl[wr*64 + i*16 + fm][fg*8];
            bh[i] = *(const short8_t*)&sBh[wc*64 + i*16 + fm][fg*8];
            bl[i] = *(const short8_t*)&sBl[wc*64 + i*16 + fm][fg*8];
        }
#pragma unroll
        for (int i=0;i<4;++i)
#pragma unroll
            for (int j=0;j<4;++j) {
                acc[i][j] = __builtin_amdgcn_mfma_f32_16x16x32_bf16(ah[i], bh[j], acc[i][j], 0,0,0);
                acc[i][j] = __builtin_amdgcn_mfma_f32_16x16x32_bf16(ah[i], bl[j], acc[i][j], 0,0,0);
                acc[i][j] = __builtin_amdgcn_mfma_f32_16x16x32_bf16(al[i], bh[j], acc[i][j], 0,0,0);
            }
    }
#pragma unroll
    for (int i=0;i<4;++i)
#pragma unroll
        for (int j4=0;j4<4;++j4) {
            const int row = bm + wr*64 + i*16 + fg*4 + j4;
            float* cr = C + (long)row*(2*DI_) + bn + wc*64 + fm;
#pragma unroll
            for (int j=0;j<4;++j) cr[j*16] = acc[i][j][j4];
        }
}

/* ---------------- split-bf16 MFMA GEMM (out): A packed (hi|lo<<16) [M,K=512],
   B pre-split [256,512]; scatter to (B,L,V,D) duplicated. ---------------- */
__global__ __launch_bounds__(256,2) void mfma_gemm_out(
    const uint* __restrict__ Apk,
    const ushort* __restrict__ Bh, const ushort* __restrict__ Bl,
    float* __restrict__ Cout)
{
    const int v = blockIdx.z;
    Apk += (long)v*ML*DI_;
    const long Bo = (long)v*D_*DI_;
    const int bm = blockIdx.y*128, bn = blockIdx.x*128;
    __shared__ ushort sAh[128][40], sAl[128][40], sBh[128][40], sBl[128][40];
    const int tid  = threadIdx.x;
    const int lane = tid & 63, w = tid >> 6;
    const int wr = w >> 1, wc = w & 1;
    const int fm = lane & 15, fg = lane >> 4;
    const int r = tid >> 1, hh = tid & 1, q0 = (tid & 1)*2;

    f32x4_t acc[4][4];
#pragma unroll
    for (int i=0;i<4;++i)
#pragma unroll
        for (int j=0;j<4;++j)
#pragma unroll
            for (int k=0;k<4;++k) acc[i][j][k]=0.f;

    const uint*   Ag  = Apk + (long)(bm+r)*DI_ + hh*16;
    const ushort* Bgh = Bh + Bo + (long)(bn+r)*DI_ + q0*8;
    const ushort* Bgl = Bl + Bo + (long)(bn+r)*DI_ + q0*8;

    for (int k0 = 0; k0 < DI_; k0 += 32) {
        const uint4 p0 = *(const uint4*)(Ag + k0);
        const uint4 p1 = *(const uint4*)(Ag + k0 + 4);
        const uint4 p2 = *(const uint4*)(Ag + k0 + 8);
        const uint4 p3 = *(const uint4*)(Ag + k0 + 12);
        const uint4 b0 = *(const uint4*)(Bgh + k0);
        const uint4 b1 = *(const uint4*)(Bgh + k0 + 8);
        const uint4 b2 = *(const uint4*)(Bgl + k0);
        const uint4 b3 = *(const uint4*)(Bgl + k0 + 8);
        __syncthreads();
        *(short4*)&sAh[r][hh*16+ 0] = make_short4((short)(p0.x&0xffff),(short)(p0.y&0xffff),(short)(p0.z&0xffff),(short)(p0.w&0xffff));
        *(short4*)&sAl[r][hh*16+ 0] = make_short4((short)(p0.x>>16),(short)(p0.y>>16),(short)(p0.z>>16),(short)(p0.w>>16));
        *(short4*)&sAh[r][hh*16+ 4] = make_short4((short)(p1.x&0xffff),(short)(p1.y&0xffff),(short)(p1.z&0xffff),(short)(p1.w&0xffff));
        *(short4*)&sAl[r][hh*16+ 4] = make_short4((short)(p1.x>>16),(short)(p1.y>>16),(short)(p1.z>>16),(short)(p1.w>>16));
        *(short4*)&sAh[r][hh*16+ 8] = make_short4((short)(p2.x&0xffff),(short)(p2.y&0xffff),(short)(p2.z&0xffff),(short)(p2.w&0xffff));
        *(short4*)&sAl[r][hh*16+ 8] = make_short4((short)(p2.x>>16),(short)(p2.y>>16),(short)(p2.z>>16),(short)(p2.w>>16));
        *(short4*)&sAh[r][hh*16+12] = make_short4((short)(p3.x&0xffff),(short)(p3.y&0xffff),(short)(p3.z&0xffff),(short)(p3.w&0xffff));
        *(short4*)&sAl[r][hh*16+12] = make_short4((short)(p3.x>>16),(short)(p3.y>>16),(short)(p3.z>>16),(short)(p3.w>>16));
        *(uint4*)&sBh[r][q0*8]   = b0;  *(uint4*)&sBh[r][q0*8+8] = b1;
        *(uint4*)&sBl[r][q0*8]   = b2;  *(uint4*)&sBl[r][q0*8+8] = b3;
        __syncthreads();
        short8_t ah[4], al[4], bh[4], bl[4];
#pragma unroll
        for (int i=0;i<4;++i) {
            ah[i] = *(const short8_t*)&sAh[wr*64 + i*16 + fm][fg*8];
            al[i] = *(const short8_t*)&sAl[wr*64 + i*16 + fm][fg*8];
            bh[i] = *(const short8_t*)&sBh[wc*64 + i*16 + fm][fg*8];
            bl[i] = *(const short8_t*)&sBl[wc*64 + i*16 + fm][fg*8];
        }
#pragma unroll
        for (int i=0;i<4;++i)
#pragma unroll
            for (int j=0;j<4;++j) {
                acc[i][j] = __builtin_amdgcn_mfma_f32_16x16x32_bf16(ah[i], bh[j], acc[i][j], 0,0,0);
                acc[i][j] = __builtin_amdgcn_mfma_f32_16x16x32_bf16(ah[i], bl[j], acc[i][j], 0,0,0);
                acc[i][j] = __builtin_amdgcn_mfma_f32_16x16x32_bf16(al[i], bh[j], acc[i][j], 0,0,0);
            }
    }
    const long TOT = (long)ML * V_ * D_;
#pragma unroll
    for (int i=0;i<4;++i)
#pragma unroll
        for (int j4=0;j4<4;++j4) {
            const int row = bm + wr*64 + i*16 + fg*4 + j4;
#pragma unroll
            for (int j=0;j<4;++j) {
                const int col = bn + wc*64 + j*16 + fm;
                const long base = ((long)row*V_ + v)*D_ + col;
                const float val = acc[i][j][j4];
                Cout[base]       = val;
                Cout[base + TOT] = val;
            }
        }
}

/* ---------------- depthwise causal conv (DCONV=4) + bias + SiLU ---------------- */
__global__ __launch_bounds__(512) void conv_silu(const float* __restrict__ xz,
                                                 const float* __restrict__ cw,
                                                 const float* __restrict__ cb,
                                                 float* __restrict__ xc)
{
    const int m = blockIdx.x;
    const int v = blockIdx.y;
    const int c = threadIdx.x;
    const int l = m & 511;
    const float* xzv = xz + (long)v*ML*2*DI_;
    const float4 w4 = *(const float4*)&cw[((long)v*DI_ + c)*4];
    const float w[4] = {w4.x, w4.y, w4.z, w4.w};
    float acc = cb[v*DI_ + c];
#pragma unroll
    for (int k = 0; k < 4; ++k) {
        const int lp = l - 3 + k;
        if (lp >= 0) acc = fmaf(xzv[(long)(m - 3 + k)*(2*DI_) + c], w[k], acc);
    }
    xc[((long)v*ML + m)*DI_ + c] = silu_f(acc);
}

/* ---------------- GEMM variant for w_x: N=48 (fp32) ---------------- */
__global__ __launch_bounds__(256) void gemm_nt48(const float* __restrict__ A,
                                                 const float* __restrict__ B,
                                                 float* __restrict__ C,
                                                 int K, long sAv, long sBv, long sCv)
{
    const int v = blockIdx.z;
    A += (long)v * sAv;  B += (long)v * sBv;  C += (long)v * sCv;
    __shared__ float As[16][68];
    __shared__ float Bs[16][48];
    const int tid = threadIdx.x;
    const int tx = tid & 15, ty = tid >> 4;
    const int bm = blockIdx.y * 64;
    const int lr = tid >> 2;
    const int lk = (tid & 3) * 4;
    const float* Ag = A + (long)(bm + lr)*K + lk;
    float acc[4][3] = {};
    for (int k0 = 0; k0 < K; k0 += 16) {
        const float4 av = *(const float4*)(Ag + k0);
        float4 bv = {0,0,0,0};
        if (tid < 192) bv = *(const float4*)(B + (long)(tid >> 2)*K + k0 + (tid & 3)*4);
        __syncthreads();
        As[lk+0][lr]=av.x; As[lk+1][lr]=av.y; As[lk+2][lr]=av.z; As[lk+3][lr]=av.w;
        if (tid < 192) {
            const int br = tid >> 2, bk = (tid & 3)*4;
            Bs[bk+0][br]=bv.x; Bs[bk+1][br]=bv.y; Bs[bk+2][br]=bv.z; Bs[bk+3][br]=bv.w;
        }
        __syncthreads();
#pragma unroll
        for (int kk = 0; kk < 16; ++kk) {
            const float4 a = *(const float4*)&As[kk][ty*4];
            const float b0 = Bs[kk][tx*3+0], b1 = Bs[kk][tx*3+1], b2 = Bs[kk][tx*3+2];
            acc[0][0]=fmaf(a.x,b0,acc[0][0]); acc[0][1]=fmaf(a.x,b1,acc[0][1]); acc[0][2]=fmaf(a.x,b2,acc[0][2]);
            acc[1][0]=fmaf(a.y,b0,acc[1][0]); acc[1][1]=fmaf(a.y,b1,acc[1][1]); acc[1][2]=fmaf(a.y,b2,acc[1][2]);
            acc[2][0]=fmaf(a.z,b0,acc[2][0]); acc[2][1]=fmaf(a.z,b1,acc[2][1]); acc[2][2]=fmaf(a.z,b2,acc[2][2]);
            acc[3][0]=fmaf(a.w,b0,acc[3][0]); acc[3][1]=fmaf(a.w,b1,acc[3][1]); acc[3][2]=fmaf(a.w,b2,acc[3][2]);
        }
    }
#pragma unroll
    for (int i = 0; i < 4; ++i)
#pragma unroll
        for (int j = 0; j < 3; ++j)
            C[(long)(bm + ty*4 + i)*48 + tx*3 + j] = acc[i][j];
}

/* ---------------- delta = softplus(dt_lo @ w_dt^T + b_dt) -> xz[:, :512] ---------------- */
__global__ __launch_bounds__(512) void delta_kernel(const float* __restrict__ xdbl,
                                                    const float* __restrict__ wdt,
                                                    const float* __restrict__ bdt,
                                                    float* __restrict__ xz)
{
    const int m = blockIdx.x;
    const int v = blockIdx.y;
    const int d = threadIdx.x;
    const float* xd = xdbl + ((long)v*ML + m)*48;
    const float* wr = wdt + ((long)v*DI_ + d)*DTR_;
    float acc = bdt[v*DI_ + d];
#pragma unroll
    for (int r = 0; r < 16; ++r) acc = fmaf(xd[r], wr[r], acc);
    const float sp = fmaxf(acc, 0.f) + log1pf(expf(-fabsf(acc)));
    xz[((long)v*ML + m)*(2*DI_) + d] = sp;
}

/* ================= chunked parallel scan (A: local, B: combine, C: seeded + epilogue) ========= */
__global__ __launch_bounds__(256) void scanA(const float* __restrict__ xz,
                                             const float* __restrict__ xcin,
                                             const float* __restrict__ xdbl,
                                             const float* __restrict__ A_log,
                                             float* __restrict__ hbuf,
                                             float* __restrict__ sdel)
{
    const int c = blockIdx.x >> 1, half = blockIdx.x & 1;
    const int b = blockIdx.y, v = blockIdx.z;
    const int d = half*256 + threadIdx.x;
    const long rowbase = (long)v*ML + (long)b*L_ + (long)c*CL_;
    const float* xzv = xz   + rowbase*(2*DI_);
    const float* xcv = xcin + rowbase*DI_;
    const float* xdv = xdbl + rowbase*48;

    __shared__ float sB[CL_][16];
    {
        int t = threadIdx.x;
        sB[t>>4][t&15] = xdv[(long)(t>>4)*48 + 16 + (t&15)];
        t += 256;
        sB[t>>4][t&15] = xdv[(long)(t>>4)*48 + 16 + (t&15)];
    }
    float a2[16];
#pragma unroll
    for (int n = 0; n < 16; ++n)
        a2[n] = -expf(A_log[((long)v*DI_ + d)*DS_ + n]) * 1.44269504088896341f;
    float h[16];
#pragma unroll
    for (int n = 0; n < 16; ++n) h[n] = 0.f;
    float sd = 0.f;
    __syncthreads();

    for (int g = 0; g < CL_; g += 8) {
        float dl[8], xr[8];
#pragma unroll
        for (int s = 0; s < 8; ++s) {
            dl[s] = xzv[(long)(g+s)*(2*DI_) + d];
            xr[s] = xcv[(long)(g+s)*DI_ + d];
        }
#pragma unroll
        for (int s = 0; s < 8; ++s) {
            const float delta = dl[s];
            const float t1 = delta * xr[s];
            sd += delta;
#pragma unroll
            for (int n = 0; n < 16; ++n)
                h[n] = fmaf(exp2f(delta*a2[n]), h[n], t1*sB[g+s][n]);
        }
    }
    float* hb = hbuf + ((((long)v*B_ + b)*NC_ + c)*DI_ + d)*16;
#pragma unroll
    for (int n = 0; n < 16; n += 4) {
        float4 r; r.x = h[n]; r.y = h[n+1]; r.z = h[n+2]; r.w = h[n+3];
        *(float4*)&hb[n] = r;
    }
    sdel[(((long)v*B_ + b)*NC_ + c)*DI_ + d] = sd;
}

__global__ __launch_bounds__(256) void scanB(const float* __restrict__ A_log,
                                             const float* __restrict__ sdel,
                                             float* __restrict__ hbuf)
{
    const long lin = (long)blockIdx.x*256 + threadIdx.x;
    const int n = (int)(lin & 15);
    const int d = (int)((lin >> 4) & 511);
    const int b = (int)((lin >> 13) & 3);
    const int v = (int)(lin >> 15);
    const float a2 = -expf(A_log[((long)v*DI_ + d)*DS_ + n]) * 1.44269504088896341f;
    float h = 0.f;
    long hidx = ((long)(v*B_ + b)*NC_)*DI_*16 + (long)d*16 + n;
    long sidx = ((long)(v*B_ + b)*NC_)*DI_ + d;
#pragma unroll
    for (int c = 0; c < NC_; ++c) {
        const float he = hbuf[hidx];
        const float P  = exp2f(a2 * sdel[sidx]);
        hbuf[hidx] = h;
        h = fmaf(P, h, he);
        hidx += (long)DI_*16;
        sidx += DI_;
    }
}

/* scanC: seeded local scan + skip + gate; writes PACKED bf16 hi|lo<<16 in-place over xc */
__global__ __launch_bounds__(256) void scanC(const float* __restrict__ xz,
                                             const float* __restrict__ xcin,
                                             const float* __restrict__ xdbl,
                                             const float* __restrict__ A_log,
                                             const float* __restrict__ D_skip,
                                             const float* __restrict__ hbuf,
                                             float* __restrict__ yout)
{
    const int c = blockIdx.x >> 1, half = blockIdx.x & 1;
    const int b = blockIdx.y, v = blockIdx.z;
    const int d = half*256 + threadIdx.x;
    const long rowbase = (long)v*ML + (long)b*L_ + (long)c*CL_;
    const float* xzv = xz   + rowbase*(2*DI_);
    const float* xcv = xcin + rowbase*DI_;
    const float* xdv = xdbl + rowbase*48;
    uint*        yv  = (uint*)yout + rowbase*DI_;

    __shared__ float sBC[CL_][32];
    for (int t = threadIdx.x; t < CL_*32; t += 256)
        sBC[t>>5][t&31] = xdv[(long)(t>>5)*48 + 16 + (t&31)];

    float a2[16];
#pragma unroll
    for (int n = 0; n < 16; ++n)
        a2[n] = -expf(A_log[((long)v*DI_ + d)*DS_ + n]) * 1.44269504088896341f;
    const float dsk = D_skip[v*DI_ + d];
    float h[16];
    const float* hb = hbuf + ((((long)v*B_ + b)*NC_ + c)*DI_ + d)*16;
#pragma unroll
    for (int n = 0; n < 16; n += 4) {
        const float4 r = *(const float4*)&hb[n];
        h[n] = r.x; h[n+1] = r.y; h[n+2] = r.z; h[n+3] = r.w;
    }
    __syncthreads();

    for (int g = 0; g < CL_; g += 8) {
        float dl[8], xr[8], zr[8];
#pragma unroll
        for (int s = 0; s < 8; ++s) {
            dl[s] = xzv[(long)(g+s)*(2*DI_) + d];
            zr[s] = xzv[(long)(g+s)*(2*DI_) + DI_ + d];
            xr[s] = xcv[(long)(g+s)*DI_ + d];
        }
#pragma unroll
        for (int s = 0; s < 8; ++s) {
            const float delta = dl[s], xcval = xr[s];
            const float t1 = delta * xcval;
            float ys = 0.f;
#pragma unroll
            for (int n = 0; n < 16; ++n) {
                const float e = exp2f(delta*a2[n]);
                h[n] = fmaf(e, h[n], t1*sBC[g+s][n]);
                ys   = fmaf(h[n], sBC[g+s][16+n], ys);
            }
            float outv = ys + xcval * dsk;
            outv *= silu_f(zr[s]);
            const ushort hv = f2bf(outv);
            const ushort lv = f2bf(outv - bf2f(hv));
            yv[(long)(g+s)*DI_ + d] = (uint)hv | ((uint)lv << 16);
        }
    }
}

extern "C" void kernel_launch(void* const* d_in, const int* in_sizes, int n_in,
                              void* d_out, int out_size, void* d_ws, size_t ws_size,
                              hipStream_t stream)
{
    const float* x      = (const float*)d_in[0];
    const float* ln_g   = (const float*)d_in[1];
    const float* ln_b   = (const float*)d_in[2];
    const float* w_in   = (const float*)d_in[3];
    const float* conv_w = (const float*)d_in[4];
    const float* conv_b = (const float*)d_in[5];
    const float* w_x    = (const float*)d_in[6];
    const float* w_dt   = (const float*)d_in[7];
    const float* b_dt   = (const float*)d_in[8];
    const float* A_log  = (const float*)d_in[9];
    const float* D_skip = (const float*)d_in[10];
    const float* w_out  = (const float*)d_in[11];
    float* out = (float*)d_out;

    float* ws   = (float*)d_ws;
    float* xz   = ws + OFF_XZ;
    float* xc   = ws + OFF_XC;
    float* xdbl = ws + OFF_XDBL;
    float* sdel = ws + OFF_SDEL;
    float* hbuf = ws + OFF_RA;

    /* region RA: xln hi/lo (each V*ML*D ushorts) */
    ushort* xlnh = (ushort*)(ws + OFF_RA);
    ushort* xlnl = xlnh + (long)V_*ML*D_;
    /* region XC head: w_in hi/lo (each V*1024*256 ushorts), dead once conv writes xc */
    ushort* wih = (ushort*)(ws + OFF_XC);
    ushort* wil = wih + (long)V_*(2*DI_)*D_;
    /* region RA tail-life: w_out hi/lo (each V*256*512 ushorts), after scanC */
    ushort* woh = (ushort*)(ws + OFF_RA);
    ushort* wol = woh + (long)V_*D_*DI_;

    /* 1. weight split for gemm-in */
    split_w<<<dim3((V_*(2*DI_)*D_/4 + 255)/256), 256, 0, stream>>>(w_in, wih, wil, V_*(2*DI_)*D_/4);

    /* 2. LayerNorm fused with hi/lo split */
    ln_split<<<dim3(ML, V_), 256, 0, stream>>>(x, ln_g, ln_b, xlnh, xlnl);

    /* 3. xz = xln @ w_in^T via 3-term split-bf16 MFMA */
    mfma_gemm_in<<<dim3((2*DI_)/128, ML/128, V_), 256, 0, stream>>>(xlnh, xlnl, wih, wil, xz);

    /* 4. depthwise causal conv + SiLU -> xc f32 (overwrites wi hi/lo) */
    conv_silu<<<dim3(ML, V_), DI_, 0, stream>>>(xz, conv_w, conv_b, xc);

    /* 5. xdbl = xc @ w_x^T (fp32) */
    gemm_nt48<<<dim3(1, ML/64, V_), 256, 0, stream>>>(
        xc, w_x, xdbl, DI_, (long)ML*DI_, (long)48*DI_, (long)ML*48);

    /* 6. delta -> xz[:, :512] */
    delta_kernel<<<dim3(ML, V_), DI_, 0, stream>>>(xdbl, w_dt, b_dt, xz);

    /* 7. chunked parallel scan; scanC writes packed bf16 y in-place over xc */
    scanA<<<dim3(NC_*2, B_, V_), 256, 0, stream>>>(xz, xc, xdbl, A_log, hbuf, sdel);
    scanB<<<dim3((V_*B_*DI_*DS_)/256), 256, 0, stream>>>(A_log, sdel, hbuf);
    scanC<<<dim3(NC_*2, B_, V_), 256, 0, stream>>>(xz, xc, xdbl, A_log, D_skip, hbuf, xc);

    /* 8. weight split for gemm-out (into hbuf region, now dead) */
    split_w<<<dim3((V_*D_*DI_/4 + 255)/256), 256, 0, stream>>>(w_out, woh, wol, V_*D_*DI_/4);

    /* 9. out = y @ w_out^T via 3-term split-bf16 MFMA, scattered + duplicated */
    mfma_gemm_out<<<dim3(D_/128, ML/128, V_), 256, 0, stream>>>((const uint*)xc, woh, wol, out);
}

// Round 6
// 265.969 us; speedup vs baseline: 1.8764x; 1.0205x over previous
//
#include <hip/hip_runtime.h>
#include <hip/hip_bf16.h>
#include <math.h>

#define B_ 4
#define L_ 512
#define V_ 4
#define D_ 256
#define DS_ 16
#define DI_ 512
#define DTR_ 16
#define ML (B_*L_)              /* 2048 rows per view */
#define NC_ 16                  /* scan chunks */
#define CL_ 32                  /* steps per chunk = L_/NC_ */

/* workspace layout (floats)
   REGION RA: xln hi/lo (pre-gemm_in) -> hbuf (scan) -> w_out hi/lo (post-scanC)
   REGION XC: w_in hi/lo (pre-gemm_in) -> xc f32 (conv..scanC) -> packed y (scanC, in-place)
   xz xi-half (cols 0..511): xi (conv input) -> nt48 split-K partials (cols 0..191) */
#define OFF_RA   0
#define SZ_RA    ((long)V_*ML*D_)          /* 2,097,152 floats */
#define OFF_XZ   (OFF_RA + SZ_RA)
#define SZ_XZ    ((long)V_*ML*2*DI_)       /* 8,388,608 */
#define OFF_XC   (OFF_XZ + SZ_XZ)
#define SZ_XC    ((long)V_*ML*DI_)         /* 4,194,304 */
#define OFF_XDBL (OFF_XC + SZ_XC)
#define SZ_XDBL  ((long)V_*ML*48)
#define OFF_SDEL (OFF_XDBL + SZ_XDBL)
#define SZ_SDEL  ((long)V_*B_*NC_*DI_)

typedef short short8_t __attribute__((ext_vector_type(8)));
typedef float f32x4_t  __attribute__((ext_vector_type(4)));

__device__ __forceinline__ float silu_f(float x) { return x / (1.f + expf(-x)); }
/* f32 -> bf16 round-to-nearest-even */
__device__ __forceinline__ ushort f2bf(float f) {
    uint u = __float_as_uint(f);
    return (ushort)((u + 0x7fffu + ((u >> 16) & 1u)) >> 16);
}
__device__ __forceinline__ float bf2f(ushort h) { return __uint_as_float(((uint)h) << 16); }

/* ---------------- weight hi/lo split (vectorized float4) ---------------- */
__global__ __launch_bounds__(256) void split_w(const float* __restrict__ in,
                                               ushort* __restrict__ oh,
                                               ushort* __restrict__ ol, int n4)
{
    const int i = blockIdx.x*256 + threadIdx.x;
    if (i >= n4) return;
    const float4 f = ((const float4*)in)[i];
    const ushort h0=f2bf(f.x), h1=f2bf(f.y), h2=f2bf(f.z), h3=f2bf(f.w);
    ((short4*)oh)[i] = make_short4((short)h0,(short)h1,(short)h2,(short)h3);
    ((short4*)ol)[i] = make_short4((short)f2bf(f.x-bf2f(h0)), (short)f2bf(f.y-bf2f(h1)),
                                   (short)f2bf(f.z-bf2f(h2)), (short)f2bf(f.w-bf2f(h3)));
}

/* ---------------- LayerNorm fused with hi/lo split ---------------- */
__global__ __launch_bounds__(256) void ln_split(const float* __restrict__ x,
                                                const float* __restrict__ g,
                                                const float* __restrict__ bta,
                                                ushort* __restrict__ xh,
                                                ushort* __restrict__ xl)
{
    const int m = blockIdx.x;
    const int v = blockIdx.y;
    const int d = threadIdx.x;
    const float val = x[((long)m*V_ + v)*D_ + d];
    float s = val, sq = val*val;
#pragma unroll
    for (int off = 32; off >= 1; off >>= 1) {
        s  += __shfl_xor(s, off);
        sq += __shfl_xor(sq, off);
    }
    __shared__ float ws[4], wq[4];
    if ((threadIdx.x & 63) == 0) { ws[threadIdx.x >> 6] = s; wq[threadIdx.x >> 6] = sq; }
    __syncthreads();
    s  = ws[0]+ws[1]+ws[2]+ws[3];
    sq = wq[0]+wq[1]+wq[2]+wq[3];
    const float mu  = s * (1.f/D_);
    const float var = sq * (1.f/D_) - mu*mu;
    const float inv = rsqrtf(var + 1e-5f);
    const float r = (val - mu)*inv*g[v*D_+d] + bta[v*D_+d];
    const ushort h = f2bf(r);
    const long idx = ((long)v*ML + m)*D_ + d;
    xh[idx] = h;
    xl[idx] = f2bf(r - bf2f(h));
}

/* ---------------- split-bf16 MFMA GEMM (in) ---------------- */
__global__ __launch_bounds__(256,2) void mfma_gemm_in(
    const ushort* __restrict__ Ah, const ushort* __restrict__ Al,
    const ushort* __restrict__ Bh, const ushort* __restrict__ Bl,
    float* __restrict__ C)
{
    const int v = blockIdx.z;
    const long Ao = (long)v*ML*D_;
    const long Bo = (long)v*(2*DI_)*D_;
    C += (long)v*ML*(2*DI_);
    const int bm = blockIdx.y*128, bn = blockIdx.x*128;
    __shared__ ushort sAh[128][40], sAl[128][40], sBh[128][40], sBl[128][40];
    const int tid  = threadIdx.x;
    const int lane = tid & 63, w = tid >> 6;
    const int wr = w >> 1, wc = w & 1;
    const int fm = lane & 15, fg = lane >> 4;
    const int r = tid >> 1, q0 = (tid & 1)*2;

    f32x4_t acc[4][4];
#pragma unroll
    for (int i=0;i<4;++i)
#pragma unroll
        for (int j=0;j<4;++j)
#pragma unroll
            for (int k=0;k<4;++k) acc[i][j][k]=0.f;

    const ushort* Agh = Ah + Ao + (long)(bm+r)*D_ + q0*8;
    const ushort* Agl = Al + Ao + (long)(bm+r)*D_ + q0*8;
    const ushort* Bgh = Bh + Bo + (long)(bn+r)*D_ + q0*8;
    const ushort* Bgl = Bl + Bo + (long)(bn+r)*D_ + q0*8;

    for (int k0 = 0; k0 < D_; k0 += 32) {
        const uint4 a0 = *(const uint4*)(Agh + k0);
        const uint4 a1 = *(const uint4*)(Agh + k0 + 8);
        const uint4 a2 = *(const uint4*)(Agl + k0);
        const uint4 a3 = *(const uint4*)(Agl + k0 + 8);
        const uint4 b0 = *(const uint4*)(Bgh + k0);
        const uint4 b1 = *(const uint4*)(Bgh + k0 + 8);
        const uint4 b2 = *(const uint4*)(Bgl + k0);
        const uint4 b3 = *(const uint4*)(Bgl + k0 + 8);
        __syncthreads();
        *(uint4*)&sAh[r][q0*8]   = a0;  *(uint4*)&sAh[r][q0*8+8] = a1;
        *(uint4*)&sAl[r][q0*8]   = a2;  *(uint4*)&sAl[r][q0*8+8] = a3;
        *(uint4*)&sBh[r][q0*8]   = b0;  *(uint4*)&sBh[r][q0*8+8] = b1;
        *(uint4*)&sBl[r][q0*8]   = b2;  *(uint4*)&sBl[r][q0*8+8] = b3;
        __syncthreads();
        short8_t ah[4], al[4], bh[4], bl[4];
#pragma unroll
        for (int i=0;i<4;++i) {
            ah[i] = *(const short8_t*)&sAh[wr*64 + i*16 + fm][fg*8];
            al[i] = *(const short8_t*)&sAl[wr*64 + i*16 + fm][fg*8];
            bh[i] = *(const short8_t*)&sBh[wc*64 + i*16 + fm][fg*8];
            bl[i] = *(const short8_t*)&sBl[wc*64 + i*16 + fm][fg*8];
        }
#pragma unroll
        for (int i=0;i<4;++i)
#pragma unroll
            for (int j=0;j<4;++j) {
                acc[i][j] = __builtin_amdgcn_mfma_f32_16x16x32_bf16(ah[i], bh[j], acc[i][j], 0,0,0);
                acc[i][j] = __builtin_amdgcn_mfma_f32_16x16x32_bf16(ah[i], bl[j], acc[i][j], 0,0,0);
                acc[i][j] = __builtin_amdgcn_mfma_f32_16x16x32_bf16(al[i], bh[j], acc[i][j], 0,0,0);
            }
    }
#pragma unroll
    for (int i=0;i<4;++i)
#pragma unroll
        for (int j4=0;j4<4;++j4) {
            const int row = bm + wr*64 + i*16 + fg*4 + j4;
            float* cr = C + (long)row*(2*DI_) + bn + wc*64 + fm;
#pragma unroll
            for (int j=0;j<4;++j) cr[j*16] = acc[i][j][j4];
        }
}

/* ---------------- split-bf16 MFMA GEMM (out) ---------------- */
__global__ __launch_bounds__(256,2) void mfma_gemm_out(
    const uint* __restrict__ Apk,
    const ushort* __restrict__ Bh, const ushort* __restrict__ Bl,
    float* __restrict__ Cout)
{
    const int v = blockIdx.z;
    Apk += (long)v*ML*DI_;
    const long Bo = (long)v*D_*DI_;
    const int bm = blockIdx.y*128, bn = blockIdx.x*128;
    __shared__ ushort sAh[128][40], sAl[128][40], sBh[128][40], sBl[128][40];
    const int tid  = threadIdx.x;
    const int lane = tid & 63, w = tid >> 6;
    const int wr = w >> 1, wc = w & 1;
    const int fm = lane & 15, fg = lane >> 4;
    const int r = tid >> 1, hh = tid & 1, q0 = (tid & 1)*2;

    f32x4_t acc[4][4];
#pragma unroll
    for (int i=0;i<4;++i)
#pragma unroll
        for (int j=0;j<4;++j)
#pragma unroll
            for (int k=0;k<4;++k) acc[i][j][k]=0.f;

    const uint*   Ag  = Apk + (long)(bm+r)*DI_ + hh*16;
    const ushort* Bgh = Bh + Bo + (long)(bn+r)*DI_ + q0*8;
    const ushort* Bgl = Bl + Bo + (long)(bn+r)*DI_ + q0*8;

    for (int k0 = 0; k0 < DI_; k0 += 32) {
        const uint4 p0 = *(const uint4*)(Ag + k0);
        const uint4 p1 = *(const uint4*)(Ag + k0 + 4);
        const uint4 p2 = *(const uint4*)(Ag + k0 + 8);
        const uint4 p3 = *(const uint4*)(Ag + k0 + 12);
        const uint4 b0 = *(const uint4*)(Bgh + k0);
        const uint4 b1 = *(const uint4*)(Bgh + k0 + 8);
        const uint4 b2 = *(const uint4*)(Bgl + k0);
        const uint4 b3 = *(const uint4*)(Bgl + k0 + 8);
        __syncthreads();
        *(short4*)&sAh[r][hh*16+ 0] = make_short4((short)(p0.x&0xffff),(short)(p0.y&0xffff),(short)(p0.z&0xffff),(short)(p0.w&0xffff));
        *(short4*)&sAl[r][hh*16+ 0] = make_short4((short)(p0.x>>16),(short)(p0.y>>16),(short)(p0.z>>16),(short)(p0.w>>16));
        *(short4*)&sAh[r][hh*16+ 4] = make_short4((short)(p1.x&0xffff),(short)(p1.y&0xffff),(short)(p1.z&0xffff),(short)(p1.w&0xffff));
        *(short4*)&sAl[r][hh*16+ 4] = make_short4((short)(p1.x>>16),(short)(p1.y>>16),(short)(p1.z>>16),(short)(p1.w>>16));
        *(short4*)&sAh[r][hh*16+ 8] = make_short4((short)(p2.x&0xffff),(short)(p2.y&0xffff),(short)(p2.z&0xffff),(short)(p2.w&0xffff));
        *(short4*)&sAl[r][hh*16+ 8] = make_short4((short)(p2.x>>16),(short)(p2.y>>16),(short)(p2.z>>16),(short)(p2.w>>16));
        *(short4*)&sAh[r][hh*16+12] = make_short4((short)(p3.x&0xffff),(short)(p3.y&0xffff),(short)(p3.z&0xffff),(short)(p3.w&0xffff));
        *(short4*)&sAl[r][hh*16+12] = make_short4((short)(p3.x>>16),(short)(p3.y>>16),(short)(p3.z>>16),(short)(p3.w>>16));
        *(uint4*)&sBh[r][q0*8]   = b0;  *(uint4*)&sBh[r][q0*8+8] = b1;
        *(uint4*)&sBl[r][q0*8]   = b2;  *(uint4*)&sBl[r][q0*8+8] = b3;
        __syncthreads();
        short8_t ah[4], al[4], bh[4], bl[4];
#pragma unroll
        for (int i=0;i<4;++i) {
            ah[i] = *(const short8_t*)&sAh[wr*64 + i*16 + fm][fg*8];
            al[i] = *(const short8_t*)&sAl[wr*64 + i*16 + fm][fg*8];
            bh[i] = *(const short8_t*)&sBh[wc*64 + i*16 + fm][fg*8];
            bl[i] = *(const short8_t*)&sBl[wc*64 + i*16 + fm][fg*8];
        }
#pragma unroll
        for (int i=0;i<4;++i)
#pragma unroll
            for (int j=0;j<4;++j) {
                acc[i][j] = __builtin_amdgcn_mfma_f32_16x16x32_bf16(ah[i], bh[j], acc[i][j], 0,0,0);
                acc[i][j] = __builtin_amdgcn_mfma_f32_16x16x32_bf16(ah[i], bl[j], acc[i][j], 0,0,0);
                acc[i][j] = __builtin_amdgcn_mfma_f32_16x16x32_bf16(al[i], bh[j], acc[i][j], 0,0,0);
            }
    }
    const long TOT = (long)ML * V_ * D_;
#pragma unroll
    for (int i=0;i<4;++i)
#pragma unroll
        for (int j4=0;j4<4;++j4) {
            const int row = bm + wr*64 + i*16 + fg*4 + j4;
#pragma unroll
            for (int j=0;j<4;++j) {
                const int col = bn + wc*64 + j*16 + fm;
                const long base = ((long)row*V_ + v)*D_ + col;
                const float val = acc[i][j][j4];
                Cout[base]       = val;
                Cout[base + TOT] = val;
            }
        }
}

/* ---------------- depthwise causal conv (DCONV=4) + bias + SiLU ---------------- */
__global__ __launch_bounds__(512) void conv_silu(const float* __restrict__ xz,
                                                 const float* __restrict__ cw,
                                                 const float* __restrict__ cb,
                                                 float* __restrict__ xc)
{
    const int m = blockIdx.x;
    const int v = blockIdx.y;
    const int c = threadIdx.x;
    const int l = m & 511;
    const float* xzv = xz + (long)v*ML*2*DI_;
    const float4 w4 = *(const float4*)&cw[((long)v*DI_ + c)*4];
    const float w[4] = {w4.x, w4.y, w4.z, w4.w};
    float acc = cb[v*DI_ + c];
#pragma unroll
    for (int k = 0; k < 4; ++k) {
        const int lp = l - 3 + k;
        if (lp >= 0) acc = fmaf(xzv[(long)(m - 3 + k)*(2*DI_) + c], w[k], acc);
    }
    xc[((long)v*ML + m)*DI_ + c] = silu_f(acc);
}

/* ---------------- gemm_nt48 split-K: partial[kslab] = A[:,ks*128:+128] @ B^T
   partials stored in dead xi half of xz: row m, cols kslab*48..+47 ---------------- */
__global__ __launch_bounds__(256) void gemm_nt48_sk(const float* __restrict__ A,
                                                    const float* __restrict__ Bm,
                                                    float* __restrict__ P,
                                                    long sAv, long sBv)
{
    const int v = blockIdx.z;
    const int ks = blockIdx.y;
    A  += (long)v * sAv;
    Bm += (long)v * sBv;
    P  += (long)v * ((long)ML*2*DI_);
    __shared__ float As[16][68];
    __shared__ float Bs[16][48];
    const int tid = threadIdx.x;
    const int tx = tid & 15, ty = tid >> 4;
    const int bm = blockIdx.x * 64;
    const int lr = tid >> 2;
    const int lk = (tid & 3) * 4;
    const float* Ag = A + (long)(bm + lr)*DI_ + lk;
    float acc[4][3] = {};
    for (int k0 = ks*128; k0 < ks*128 + 128; k0 += 16) {
        const float4 av = *(const float4*)(Ag + k0);
        float4 bv = {0,0,0,0};
        if (tid < 192) bv = *(const float4*)(Bm + (long)(tid >> 2)*DI_ + k0 + (tid & 3)*4);
        __syncthreads();
        As[lk+0][lr]=av.x; As[lk+1][lr]=av.y; As[lk+2][lr]=av.z; As[lk+3][lr]=av.w;
        if (tid < 192) {
            const int br = tid >> 2, bk = (tid & 3)*4;
            Bs[bk+0][br]=bv.x; Bs[bk+1][br]=bv.y; Bs[bk+2][br]=bv.z; Bs[bk+3][br]=bv.w;
        }
        __syncthreads();
#pragma unroll
        for (int kk = 0; kk < 16; ++kk) {
            const float4 a = *(const float4*)&As[kk][ty*4];
            const float b0 = Bs[kk][tx*3+0], b1 = Bs[kk][tx*3+1], b2 = Bs[kk][tx*3+2];
            acc[0][0]=fmaf(a.x,b0,acc[0][0]); acc[0][1]=fmaf(a.x,b1,acc[0][1]); acc[0][2]=fmaf(a.x,b2,acc[0][2]);
            acc[1][0]=fmaf(a.y,b0,acc[1][0]); acc[1][1]=fmaf(a.y,b1,acc[1][1]); acc[1][2]=fmaf(a.y,b2,acc[1][2]);
            acc[2][0]=fmaf(a.z,b0,acc[2][0]); acc[2][1]=fmaf(a.z,b1,acc[2][1]); acc[2][2]=fmaf(a.z,b2,acc[2][2]);
            acc[3][0]=fmaf(a.w,b0,acc[3][0]); acc[3][1]=fmaf(a.w,b1,acc[3][1]); acc[3][2]=fmaf(a.w,b2,acc[3][2]);
        }
    }
#pragma unroll
    for (int i = 0; i < 4; ++i)
#pragma unroll
        for (int j = 0; j < 3; ++j)
            P[(long)(bm + ty*4 + i)*(2*DI_) + ks*48 + tx*3 + j] = acc[i][j];
}

/* sum 4 k-slab partials (xi half of xz) -> xdbl */
__global__ __launch_bounds__(256) void reduce48(const float* __restrict__ xz,
                                                float* __restrict__ xdbl)
{
    const long i = (long)blockIdx.x*256 + threadIdx.x;   /* V*ML*48 = 393216 */
    if (i >= (long)V_*ML*48) return;
    const long row = i / 48; const int j = (int)(i % 48);
    const float* p = xz + row*(2*DI_);
    xdbl[i] = (p[j] + p[48+j]) + (p[96+j] + p[144+j]);
}

/* ================= chunked parallel scan, delta fused =================
   delta = softplus(dot16(xdbl_dtlo[s], w_dt[d]) + b_dt[d]) computed in-kernel.
   sX stages full xdbl rows: cols 0..15 dt_lo, 16..31 B, 32..47 C. */
__global__ __launch_bounds__(256) void scanA(const float* __restrict__ xcin,
                                             const float* __restrict__ xdbl,
                                             const float* __restrict__ A_log,
                                             const float* __restrict__ wdt,
                                             const float* __restrict__ bdt,
                                             float* __restrict__ hbuf,
                                             float* __restrict__ sdel)
{
    const int c = blockIdx.x >> 1, half = blockIdx.x & 1;
    const int b = blockIdx.y, v = blockIdx.z;
    const int d = half*256 + threadIdx.x;
    const long rowbase = (long)v*ML + (long)b*L_ + (long)c*CL_;
    const float* xcv = xcin + rowbase*DI_;
    const float* xdv = xdbl + rowbase*48;

    __shared__ float sX[CL_*48];
    for (int t = threadIdx.x; t < CL_*48; t += 256) sX[t] = xdv[t];

    float a2[16];
#pragma unroll
    for (int n = 0; n < 16; ++n)
        a2[n] = -expf(A_log[((long)v*DI_ + d)*DS_ + n]) * 1.44269504088896341f;
    float wreg[16];
    {
        const float* wp = wdt + ((long)v*DI_ + d)*DTR_;
#pragma unroll
        for (int r = 0; r < 16; r += 4) {
            const float4 t4 = *(const float4*)(wp + r);
            wreg[r]=t4.x; wreg[r+1]=t4.y; wreg[r+2]=t4.z; wreg[r+3]=t4.w;
        }
    }
    const float bias = bdt[(long)v*DI_ + d];
    float h[16];
#pragma unroll
    for (int n = 0; n < 16; ++n) h[n] = 0.f;
    float sdsum = 0.f;
    __syncthreads();

    float xcur[8], xnxt[8];
#pragma unroll
    for (int s = 0; s < 8; ++s) xcur[s] = xcv[(long)s*DI_ + d];

    for (int g = 0; g < CL_; g += 8) {
        if (g + 8 < CL_) {
#pragma unroll
            for (int s = 0; s < 8; ++s) xnxt[s] = xcv[(long)(g+8+s)*DI_ + d];
        }
#pragma unroll
        for (int s = 0; s < 8; ++s) {
            const float* xrow = &sX[(g+s)*48];
            float acc = bias;
#pragma unroll
            for (int r = 0; r < 16; ++r) acc = fmaf(xrow[r], wreg[r], acc);
            const float delta = fmaxf(acc, 0.f) + log1pf(expf(-fabsf(acc)));
            const float t1 = delta * xcur[s];
            sdsum += delta;
#pragma unroll
            for (int n = 0; n < 16; ++n)
                h[n] = fmaf(exp2f(delta*a2[n]), h[n], t1*xrow[16+n]);
        }
#pragma unroll
        for (int s = 0; s < 8; ++s) xcur[s] = xnxt[s];
    }
    float* hb = hbuf + ((((long)v*B_ + b)*NC_ + c)*DI_ + d)*16;
#pragma unroll
    for (int n = 0; n < 16; n += 4) {
        float4 r; r.x = h[n]; r.y = h[n+1]; r.z = h[n+2]; r.w = h[n+3];
        *(float4*)&hb[n] = r;
    }
    sdel[(((long)v*B_ + b)*NC_ + c)*DI_ + d] = sdsum;
}

__global__ __launch_bounds__(256) void scanB(const float* __restrict__ A_log,
                                             const float* __restrict__ sdel,
                                             float* __restrict__ hbuf)
{
    const long lin = (long)blockIdx.x*256 + threadIdx.x;
    const int n = (int)(lin & 15);
    const int d = (int)((lin >> 4) & 511);
    const int b = (int)((lin >> 13) & 3);
    const int v = (int)(lin >> 15);
    const float a2 = -expf(A_log[((long)v*DI_ + d)*DS_ + n]) * 1.44269504088896341f;
    float h = 0.f;
    long hidx = ((long)(v*B_ + b)*NC_)*DI_*16 + (long)d*16 + n;
    long sidx = ((long)(v*B_ + b)*NC_)*DI_ + d;
#pragma unroll
    for (int c = 0; c < NC_; ++c) {
        const float he = hbuf[hidx];
        const float P  = exp2f(a2 * sdel[sidx]);
        hbuf[hidx] = h;
        h = fmaf(P, h, he);
        hidx += (long)DI_*16;
        sidx += DI_;
    }
}

/* scanC: seeded local scan + skip + gate, delta fused; writes packed bf16 y over xc */
__global__ __launch_bounds__(256) void scanC(const float* __restrict__ xz,
                                             const float* __restrict__ xcin,
                                             const float* __restrict__ xdbl,
                                             const float* __restrict__ A_log,
                                             const float* __restrict__ wdt,
                                             const float* __restrict__ bdt,
                                             const float* __restrict__ D_skip,
                                             const float* __restrict__ hbuf,
                                             float* __restrict__ yout)
{
    const int c = blockIdx.x >> 1, half = blockIdx.x & 1;
    const int b = blockIdx.y, v = blockIdx.z;
    const int d = half*256 + threadIdx.x;
    const long rowbase = (long)v*ML + (long)b*L_ + (long)c*CL_;
    const float* xzv = xz   + rowbase*(2*DI_);
    const float* xcv = xcin + rowbase*DI_;
    const float* xdv = xdbl + rowbase*48;
    uint*        yv  = (uint*)yout + rowbase*DI_;

    __shared__ float sX[CL_*48];
    for (int t = threadIdx.x; t < CL_*48; t += 256) sX[t] = xdv[t];

    float a2[16];
#pragma unroll
    for (int n = 0; n < 16; ++n)
        a2[n] = -expf(A_log[((long)v*DI_ + d)*DS_ + n]) * 1.44269504088896341f;
    float wreg[16];
    {
        const float* wp = wdt + ((long)v*DI_ + d)*DTR_;
#pragma unroll
        for (int r = 0; r < 16; r += 4) {
            const float4 t4 = *(const float4*)(wp + r);
            wreg[r]=t4.x; wreg[r+1]=t4.y; wreg[r+2]=t4.z; wreg[r+3]=t4.w;
        }
    }
    const float bias = bdt[(long)v*DI_ + d];
    const float dsk = D_skip[v*DI_ + d];
    float h[16];
    const float* hb = hbuf + ((((long)v*B_ + b)*NC_ + c)*DI_ + d)*16;
#pragma unroll
    for (int n = 0; n < 16; n += 4) {
        const float4 r = *(const float4*)&hb[n];
        h[n] = r.x; h[n+1] = r.y; h[n+2] = r.z; h[n+3] = r.w;
    }
    __syncthreads();

    float xcur[8], zcur[8], xnxt[8], znxt[8];
#pragma unroll
    for (int s = 0; s < 8; ++s) {
        xcur[s] = xcv[(long)s*DI_ + d];
        zcur[s] = xzv[(long)s*(2*DI_) + DI_ + d];
    }

    for (int g = 0; g < CL_; g += 8) {
        if (g + 8 < CL_) {
#pragma unroll
            for (int s = 0; s < 8; ++s) {
                xnxt[s] = xcv[(long)(g+8+s)*DI_ + d];
                znxt[s] = xzv[(long)(g+8+s)*(2*DI_) + DI_ + d];
            }
        }
#pragma unroll
        for (int s = 0; s < 8; ++s) {
            const float* xrow = &sX[(g+s)*48];
            float acc = bias;
#pragma unroll
            for (int r = 0; r < 16; ++r) acc = fmaf(xrow[r], wreg[r], acc);
            const float delta = fmaxf(acc, 0.f) + log1pf(expf(-fabsf(acc)));
            const float xcval = xcur[s];
            const float t1 = delta * xcval;
            float ys = 0.f;
#pragma unroll
            for (int n = 0; n < 16; ++n) {
                const float e = exp2f(delta*a2[n]);
                h[n] = fmaf(e, h[n], t1*xrow[16+n]);
                ys   = fmaf(h[n], xrow[32+n], ys);
            }
            float outv = ys + xcval * dsk;
            outv *= silu_f(zcur[s]);
            const ushort hv = f2bf(outv);
            const ushort lv = f2bf(outv - bf2f(hv));
            yv[(long)(g+s)*DI_ + d] = (uint)hv | ((uint)lv << 16);
        }
#pragma unroll
        for (int s = 0; s < 8; ++s) { xcur[s] = xnxt[s]; zcur[s] = znxt[s]; }
    }
}

extern "C" void kernel_launch(void* const* d_in, const int* in_sizes, int n_in,
                              void* d_out, int out_size, void* d_ws, size_t ws_size,
                              hipStream_t stream)
{
    const float* x      = (const float*)d_in[0];
    const float* ln_g   = (const float*)d_in[1];
    const float* ln_b   = (const float*)d_in[2];
    const float* w_in   = (const float*)d_in[3];
    const float* conv_w = (const float*)d_in[4];
    const float* conv_b = (const float*)d_in[5];
    const float* w_x    = (const float*)d_in[6];
    const float* w_dt   = (const float*)d_in[7];
    const float* b_dt   = (const float*)d_in[8];
    const float* A_log  = (const float*)d_in[9];
    const float* D_skip = (const float*)d_in[10];
    const float* w_out  = (const float*)d_in[11];
    float* out = (float*)d_out;

    float* ws   = (float*)d_ws;
    float* xz   = ws + OFF_XZ;
    float* xc   = ws + OFF_XC;
    float* xdbl = ws + OFF_XDBL;
    float* sdel = ws + OFF_SDEL;
    float* hbuf = ws + OFF_RA;

    ushort* xlnh = (ushort*)(ws + OFF_RA);
    ushort* xlnl = xlnh + (long)V_*ML*D_;
    ushort* wih = (ushort*)(ws + OFF_XC);
    ushort* wil = wih + (long)V_*(2*DI_)*D_;
    ushort* woh = (ushort*)(ws + OFF_RA);
    ushort* wol = woh + (long)V_*D_*DI_;

    /* 1. weight split for gemm-in */
    split_w<<<dim3((V_*(2*DI_)*D_/4 + 255)/256), 256, 0, stream>>>(w_in, wih, wil, V_*(2*DI_)*D_/4);

    /* 2. LayerNorm fused with hi/lo split */
    ln_split<<<dim3(ML, V_), 256, 0, stream>>>(x, ln_g, ln_b, xlnh, xlnl);

    /* 3. xz = xln @ w_in^T via 3-term split-bf16 MFMA */
    mfma_gemm_in<<<dim3((2*DI_)/128, ML/128, V_), 256, 0, stream>>>(xlnh, xlnl, wih, wil, xz);

    /* 4. depthwise causal conv + SiLU -> xc f32 */
    conv_silu<<<dim3(ML, V_), DI_, 0, stream>>>(xz, conv_w, conv_b, xc);

    /* 5. xdbl = xc @ w_x^T, split-K=4 (partials in dead xi half of xz) + reduce */
    gemm_nt48_sk<<<dim3(ML/64, 4, V_), 256, 0, stream>>>(
        xc, w_x, xz, (long)ML*DI_, (long)48*DI_);
    reduce48<<<dim3((V_*ML*48 + 255)/256), 256, 0, stream>>>(xz, xdbl);

    /* 6. chunked parallel scan, delta fused into A and C */
    scanA<<<dim3(NC_*2, B_, V_), 256, 0, stream>>>(xc, xdbl, A_log, w_dt, b_dt, hbuf, sdel);
    scanB<<<dim3((V_*B_*DI_*DS_)/256), 256, 0, stream>>>(A_log, sdel, hbuf);
    scanC<<<dim3(NC_*2, B_, V_), 256, 0, stream>>>(xz, xc, xdbl, A_log, w_dt, b_dt,
                                                   D_skip, hbuf, xc);

    /* 7. weight split for gemm-out (hbuf region now dead) */
    split_w<<<dim3((V_*D_*DI_/4 + 255)/256), 256, 0, stream>>>(w_out, woh, wol, V_*D_*DI_/4);

    /* 8. out = y @ w_out^T via 3-term split-bf16 MFMA, scattered + duplicated */
    mfma_gemm_out<<<dim3(D_/128, ML/128, V_), 256, 0, stream>>>((const uint*)xc, woh, wol, out);
}

// Round 10
// 228.203 us; speedup vs baseline: 2.1869x; 1.1655x over previous
//
#include <hip/hip_runtime.h>
#include <hip/hip_bf16.h>
#include <math.h>

#define B_ 4
#define L_ 512
#define V_ 4
#define D_ 256
#define DS_ 16
#define DI_ 512
#define DTR_ 16
#define ML (B_*L_)              /* 2048 rows per view */
#define NC_ 32                  /* scan chunks */
#define CL_ 16                  /* steps per chunk = L_/NC_ */

/* workspace layout (floats)
   REGION RA: xln hi/lo (pre-gemm_in) -> sdel (scan) -> w_out hi/lo (post-scanC)
   REGION XZ xi-half (cols 0..511): xi (conv in) -> nt48 partials -> hbuf (scan)
   REGION XC: w_in hi/lo (pre-gemm_in) -> xc f32 (conv..scanC) -> packed y (scanC, in-place) */
#define OFF_RA   0
#define SZ_RA    ((long)V_*ML*D_)          /* 2,097,152 floats */
#define OFF_XZ   (OFF_RA + SZ_RA)
#define SZ_XZ    ((long)V_*ML*2*DI_)       /* 8,388,608 */
#define OFF_XC   (OFF_XZ + SZ_XZ)
#define SZ_XC    ((long)V_*ML*DI_)         /* 4,194,304 */
#define OFF_XDBL (OFF_XC + SZ_XC)
#define SZ_XDBL  ((long)V_*ML*48)

typedef short short8_t __attribute__((ext_vector_type(8)));
typedef float f32x4_t  __attribute__((ext_vector_type(4)));

#define LOG2E 1.44269504088896341f
#define LN2   0.69314718055994531f

__device__ __forceinline__ float exp2_fast(float x) { return __builtin_amdgcn_exp2f(x); }
/* softplus via native log2/exp2: log(1+e^x) = log2(1+2^(x*log2e))*ln2; x>20 -> x (err<2e-9) */
__device__ __forceinline__ float softplus_fast(float x) {
    const float t = __builtin_amdgcn_exp2f(x * LOG2E);
    const float r = __builtin_amdgcn_logf(1.f + t) * LN2;
    return x > 20.f ? x : r;
}
/* silu via native exp2 + rcp */
__device__ __forceinline__ float silu_fast(float z) {
    const float t = __builtin_amdgcn_exp2f(-LOG2E * z);
    return z * __builtin_amdgcn_rcpf(1.f + t);
}
/* f32 -> bf16 round-to-nearest-even */
__device__ __forceinline__ ushort f2bf(float f) {
    uint u = __float_as_uint(f);
    return (ushort)((u + 0x7fffu + ((u >> 16) & 1u)) >> 16);
}
__device__ __forceinline__ float bf2f(ushort h) { return __uint_as_float(((uint)h) << 16); }

/* hbuf slot base (n=0) inside xz xi-half: per view exactly ML*512 slots */
__device__ __forceinline__ long hb_idx(int v, int b, int c, int d) {
    const long s = ((((long)b*NC_ + c)*DI_ + d) << 4);   /* < 1,048,576 */
    return (long)v*ML*(2*DI_) + (s >> 9)*(2*DI_) + (s & 511);
}

/* ---------------- weight hi/lo split ---------------- */
__global__ __launch_bounds__(256) void split_w(const float* __restrict__ in,
                                               ushort* __restrict__ oh,
                                               ushort* __restrict__ ol, int n4)
{
    const int i = blockIdx.x*256 + threadIdx.x;
    if (i >= n4) return;
    const float4 f = ((const float4*)in)[i];
    const ushort h0=f2bf(f.x), h1=f2bf(f.y), h2=f2bf(f.z), h3=f2bf(f.w);
    ((short4*)oh)[i] = make_short4((short)h0,(short)h1,(short)h2,(short)h3);
    ((short4*)ol)[i] = make_short4((short)f2bf(f.x-bf2f(h0)), (short)f2bf(f.y-bf2f(h1)),
                                   (short)f2bf(f.z-bf2f(h2)), (short)f2bf(f.w-bf2f(h3)));
}

/* ---------------- LayerNorm fused with hi/lo split ---------------- */
__global__ __launch_bounds__(256) void ln_split(const float* __restrict__ x,
                                                const float* __restrict__ g,
                                                const float* __restrict__ bta,
                                                ushort* __restrict__ xh,
                                                ushort* __restrict__ xl)
{
    const int m = blockIdx.x;
    const int v = blockIdx.y;
    const int d = threadIdx.x;
    const float val = x[((long)m*V_ + v)*D_ + d];
    float s = val, sq = val*val;
#pragma unroll
    for (int off = 32; off >= 1; off >>= 1) {
        s  += __shfl_xor(s, off);
        sq += __shfl_xor(sq, off);
    }
    __shared__ float ws[4], wq[4];
    if ((threadIdx.x & 63) == 0) { ws[threadIdx.x >> 6] = s; wq[threadIdx.x >> 6] = sq; }
    __syncthreads();
    s  = ws[0]+ws[1]+ws[2]+ws[3];
    sq = wq[0]+wq[1]+wq[2]+wq[3];
    const float mu  = s * (1.f/D_);
    const float var = sq * (1.f/D_) - mu*mu;
    const float inv = rsqrtf(var + 1e-5f);
    const float r = (val - mu)*inv*g[v*D_+d] + bta[v*D_+d];
    const ushort h = f2bf(r);
    const long idx = ((long)v*ML + m)*D_ + d;
    xh[idx] = h;
    xl[idx] = f2bf(r - bf2f(h));
}

/* ---------------- split-bf16 MFMA GEMM (in) ---------------- */
__global__ __launch_bounds__(256,2) void mfma_gemm_in(
    const ushort* __restrict__ Ah, const ushort* __restrict__ Al,
    const ushort* __restrict__ Bh, const ushort* __restrict__ Bl,
    float* __restrict__ C)
{
    const int v = blockIdx.z;
    const long Ao = (long)v*ML*D_;
    const long Bo = (long)v*(2*DI_)*D_;
    C += (long)v*ML*(2*DI_);
    const int bm = blockIdx.y*128, bn = blockIdx.x*128;
    __shared__ ushort sAh[128][40], sAl[128][40], sBh[128][40], sBl[128][40];
    const int tid  = threadIdx.x;
    const int lane = tid & 63, w = tid >> 6;
    const int wr = w >> 1, wc = w & 1;
    const int fm = lane & 15, fg = lane >> 4;
    const int r = tid >> 1, q0 = (tid & 1)*2;

    f32x4_t acc[4][4];
#pragma unroll
    for (int i=0;i<4;++i)
#pragma unroll
        for (int j=0;j<4;++j)
#pragma unroll
            for (int k=0;k<4;++k) acc[i][j][k]=0.f;

    const ushort* Agh = Ah + Ao + (long)(bm+r)*D_ + q0*8;
    const ushort* Agl = Al + Ao + (long)(bm+r)*D_ + q0*8;
    const ushort* Bgh = Bh + Bo + (long)(bn+r)*D_ + q0*8;
    const ushort* Bgl = Bl + Bo + (long)(bn+r)*D_ + q0*8;

    for (int k0 = 0; k0 < D_; k0 += 32) {
        const uint4 a0 = *(const uint4*)(Agh + k0);
        const uint4 a1 = *(const uint4*)(Agh + k0 + 8);
        const uint4 a2 = *(const uint4*)(Agl + k0);
        const uint4 a3 = *(const uint4*)(Agl + k0 + 8);
        const uint4 b0 = *(const uint4*)(Bgh + k0);
        const uint4 b1 = *(const uint4*)(Bgh + k0 + 8);
        const uint4 b2 = *(const uint4*)(Bgl + k0);
        const uint4 b3 = *(const uint4*)(Bgl + k0 + 8);
        __syncthreads();
        *(uint4*)&sAh[r][q0*8]   = a0;  *(uint4*)&sAh[r][q0*8+8] = a1;
        *(uint4*)&sAl[r][q0*8]   = a2;  *(uint4*)&sAl[r][q0*8+8] = a3;
        *(uint4*)&sBh[r][q0*8]   = b0;  *(uint4*)&sBh[r][q0*8+8] = b1;
        *(uint4*)&sBl[r][q0*8]   = b2;  *(uint4*)&sBl[r][q0*8+8] = b3;
        __syncthreads();
        short8_t ah[4], al[4], bh[4], bl[4];
#pragma unroll
        for (int i=0;i<4;++i) {
            ah[i] = *(const short8_t*)&sAh[wr*64 + i*16 + fm][fg*8];
            al[i] = *(const short8_t*)&sAl[wr*64 + i*16 + fm][fg*8];
            bh[i] = *(const short8_t*)&sBh[wc*64 + i*16 + fm][fg*8];
            bl[i] = *(const short8_t*)&sBl[wc*64 + i*16 + fm][fg*8];
        }
#pragma unroll
        for (int i=0;i<4;++i)
#pragma unroll
            for (int j=0;j<4;++j) {
                acc[i][j] = __builtin_amdgcn_mfma_f32_16x16x32_bf16(ah[i], bh[j], acc[i][j], 0,0,0);
                acc[i][j] = __builtin_amdgcn_mfma_f32_16x16x32_bf16(ah[i], bl[j], acc[i][j], 0,0,0);
                acc[i][j] = __builtin_amdgcn_mfma_f32_16x16x32_bf16(al[i], bh[j], acc[i][j], 0,0,0);
            }
    }
#pragma unroll
    for (int i=0;i<4;++i)
#pragma unroll
        for (int j4=0;j4<4;++j4) {
            const int row = bm + wr*64 + i*16 + fg*4 + j4;
            float* cr = C + (long)row*(2*DI_) + bn + wc*64 + fm;
#pragma unroll
            for (int j=0;j<4;++j) cr[j*16] = acc[i][j][j4];
        }
}

/* ---------------- split-bf16 MFMA GEMM (out) ---------------- */
__global__ __launch_bounds__(256,2) void mfma_gemm_out(
    const uint* __restrict__ Apk,
    const ushort* __restrict__ Bh, const ushort* __restrict__ Bl,
    float* __restrict__ Cout)
{
    const int v = blockIdx.z;
    Apk += (long)v*ML*DI_;
    const long Bo = (long)v*D_*DI_;
    const int bm = blockIdx.y*128, bn = blockIdx.x*128;
    __shared__ ushort sAh[128][40], sAl[128][40], sBh[128][40], sBl[128][40];
    const int tid  = threadIdx.x;
    const int lane = tid & 63, w = tid >> 6;
    const int wr = w >> 1, wc = w & 1;
    const int fm = lane & 15, fg = lane >> 4;
    const int r = tid >> 1, hh = tid & 1, q0 = (tid & 1)*2;

    f32x4_t acc[4][4];
#pragma unroll
    for (int i=0;i<4;++i)
#pragma unroll
        for (int j=0;j<4;++j)
#pragma unroll
            for (int k=0;k<4;++k) acc[i][j][k]=0.f;

    const uint*   Ag  = Apk + (long)(bm+r)*DI_ + hh*16;
    const ushort* Bgh = Bh + Bo + (long)(bn+r)*DI_ + q0*8;
    const ushort* Bgl = Bl + Bo + (long)(bn+r)*DI_ + q0*8;

    for (int k0 = 0; k0 < DI_; k0 += 32) {
        const uint4 p0 = *(const uint4*)(Ag + k0);
        const uint4 p1 = *(const uint4*)(Ag + k0 + 4);
        const uint4 p2 = *(const uint4*)(Ag + k0 + 8);
        const uint4 p3 = *(const uint4*)(Ag + k0 + 12);
        const uint4 b0 = *(const uint4*)(Bgh + k0);
        const uint4 b1 = *(const uint4*)(Bgh + k0 + 8);
        const uint4 b2 = *(const uint4*)(Bgl + k0);
        const uint4 b3 = *(const uint4*)(Bgl + k0 + 8);
        __syncthreads();
        *(short4*)&sAh[r][hh*16+ 0] = make_short4((short)(p0.x&0xffff),(short)(p0.y&0xffff),(short)(p0.z&0xffff),(short)(p0.w&0xffff));
        *(short4*)&sAl[r][hh*16+ 0] = make_short4((short)(p0.x>>16),(short)(p0.y>>16),(short)(p0.z>>16),(short)(p0.w>>16));
        *(short4*)&sAh[r][hh*16+ 4] = make_short4((short)(p1.x&0xffff),(short)(p1.y&0xffff),(short)(p1.z&0xffff),(short)(p1.w&0xffff));
        *(short4*)&sAl[r][hh*16+ 4] = make_short4((short)(p1.x>>16),(short)(p1.y>>16),(short)(p1.z>>16),(short)(p1.w>>16));
        *(short4*)&sAh[r][hh*16+ 8] = make_short4((short)(p2.x&0xffff),(short)(p2.y&0xffff),(short)(p2.z&0xffff),(short)(p2.w&0xffff));
        *(short4*)&sAl[r][hh*16+ 8] = make_short4((short)(p2.x>>16),(short)(p2.y>>16),(short)(p2.z>>16),(short)(p2.w>>16));
        *(short4*)&sAh[r][hh*16+12] = make_short4((short)(p3.x&0xffff),(short)(p3.y&0xffff),(short)(p3.z&0xffff),(short)(p3.w&0xffff));
        *(short4*)&sAl[r][hh*16+12] = make_short4((short)(p3.x>>16),(short)(p3.y>>16),(short)(p3.z>>16),(short)(p3.w>>16));
        *(uint4*)&sBh[r][q0*8]   = b0;  *(uint4*)&sBh[r][q0*8+8] = b1;
        *(uint4*)&sBl[r][q0*8]   = b2;  *(uint4*)&sBl[r][q0*8+8] = b3;
        __syncthreads();
        short8_t ah[4], al[4], bh[4], bl[4];
#pragma unroll
        for (int i=0;i<4;++i) {
            ah[i] = *(const short8_t*)&sAh[wr*64 + i*16 + fm][fg*8];
            al[i] = *(const short8_t*)&sAl[wr*64 + i*16 + fm][fg*8];
            bh[i] = *(const short8_t*)&sBh[wc*64 + i*16 + fm][fg*8];
            bl[i] = *(const short8_t*)&sBl[wc*64 + i*16 + fm][fg*8];
        }
#pragma unroll
        for (int i=0;i<4;++i)
#pragma unroll
            for (int j=0;j<4;++j) {
                acc[i][j] = __builtin_amdgcn_mfma_f32_16x16x32_bf16(ah[i], bh[j], acc[i][j], 0,0,0);
                acc[i][j] = __builtin_amdgcn_mfma_f32_16x16x32_bf16(ah[i], bl[j], acc[i][j], 0,0,0);
                acc[i][j] = __builtin_amdgcn_mfma_f32_16x16x32_bf16(al[i], bh[j], acc[i][j], 0,0,0);
            }
    }
    const long TOT = (long)ML * V_ * D_;
#pragma unroll
    for (int i=0;i<4;++i)
#pragma unroll
        for (int j4=0;j4<4;++j4) {
            const int row = bm + wr*64 + i*16 + fg*4 + j4;
#pragma unroll
            for (int j=0;j<4;++j) {
                const int col = bn + wc*64 + j*16 + fm;
                const long base = ((long)row*V_ + v)*D_ + col;
                const float val = acc[i][j][j4];
                Cout[base]       = val;
                Cout[base + TOT] = val;
            }
        }
}

/* ---------------- depthwise causal conv (DCONV=4) + bias + SiLU ---------------- */
__global__ __launch_bounds__(512) void conv_silu(const float* __restrict__ xz,
                                                 const float* __restrict__ cw,
                                                 const float* __restrict__ cb,
                                                 float* __restrict__ xc)
{
    const int m = blockIdx.x;
    const int v = blockIdx.y;
    const int c = threadIdx.x;
    const int l = m & 511;
    const float* xzv = xz + (long)v*ML*2*DI_;
    const float4 w4 = *(const float4*)&cw[((long)v*DI_ + c)*4];
    const float w[4] = {w4.x, w4.y, w4.z, w4.w};
    float acc = cb[v*DI_ + c];
#pragma unroll
    for (int k = 0; k < 4; ++k) {
        const int lp = l - 3 + k;
        if (lp >= 0) acc = fmaf(xzv[(long)(m - 3 + k)*(2*DI_) + c], w[k], acc);
    }
    xc[((long)v*ML + m)*DI_ + c] = silu_fast(acc);
}

/* ---------------- gemm_nt48 split-K (partials in dead xi half of xz) ---------------- */
__global__ __launch_bounds__(256) void gemm_nt48_sk(const float* __restrict__ A,
                                                    const float* __restrict__ Bm,
                                                    float* __restrict__ P,
                                                    long sAv, long sBv)
{
    const int v = blockIdx.z;
    const int ks = blockIdx.y;
    A  += (long)v * sAv;
    Bm += (long)v * sBv;
    P  += (long)v * ((long)ML*2*DI_);
    __shared__ float As[16][68];
    __shared__ float Bs[16][48];
    const int tid = threadIdx.x;
    const int tx = tid & 15, ty = tid >> 4;
    const int bm = blockIdx.x * 64;
    const int lr = tid >> 2;
    const int lk = (tid & 3) * 4;
    const float* Ag = A + (long)(bm + lr)*DI_ + lk;
    float acc[4][3] = {};
    for (int k0 = ks*128; k0 < ks*128 + 128; k0 += 16) {
        const float4 av = *(const float4*)(Ag + k0);
        float4 bv = {0,0,0,0};
        if (tid < 192) bv = *(const float4*)(Bm + (long)(tid >> 2)*DI_ + k0 + (tid & 3)*4);
        __syncthreads();
        As[lk+0][lr]=av.x; As[lk+1][lr]=av.y; As[lk+2][lr]=av.z; As[lk+3][lr]=av.w;
        if (tid < 192) {
            const int br = tid >> 2, bk = (tid & 3)*4;
            Bs[bk+0][br]=bv.x; Bs[bk+1][br]=bv.y; Bs[bk+2][br]=bv.z; Bs[bk+3][br]=bv.w;
        }
        __syncthreads();
#pragma unroll
        for (int kk = 0; kk < 16; ++kk) {
            const float4 a = *(const float4*)&As[kk][ty*4];
            const float b0 = Bs[kk][tx*3+0], b1 = Bs[kk][tx*3+1], b2 = Bs[kk][tx*3+2];
            acc[0][0]=fmaf(a.x,b0,acc[0][0]); acc[0][1]=fmaf(a.x,b1,acc[0][1]); acc[0][2]=fmaf(a.x,b2,acc[0][2]);
            acc[1][0]=fmaf(a.y,b0,acc[1][0]); acc[1][1]=fmaf(a.y,b1,acc[1][1]); acc[1][2]=fmaf(a.y,b2,acc[1][2]);
            acc[2][0]=fmaf(a.z,b0,acc[2][0]); acc[2][1]=fmaf(a.z,b1,acc[2][1]); acc[2][2]=fmaf(a.z,b2,acc[2][2]);
            acc[3][0]=fmaf(a.w,b0,acc[3][0]); acc[3][1]=fmaf(a.w,b1,acc[3][1]); acc[3][2]=fmaf(a.w,b2,acc[3][2]);
        }
    }
#pragma unroll
    for (int i = 0; i < 4; ++i)
#pragma unroll
        for (int j = 0; j < 3; ++j)
            P[(long)(bm + ty*4 + i)*(2*DI_) + ks*48 + tx*3 + j] = acc[i][j];
}

/* sum 4 k-slab partials -> xdbl */
__global__ __launch_bounds__(256) void reduce48(const float* __restrict__ xz,
                                                float* __restrict__ xdbl)
{
    const long i = (long)blockIdx.x*256 + threadIdx.x;
    if (i >= (long)V_*ML*48) return;
    const long row = i / 48; const int j = (int)(i % 48);
    const float* p = xz + row*(2*DI_);
    xdbl[i] = (p[j] + p[48+j]) + (p[96+j] + p[144+j]);
}

/* ================= chunked parallel scan, delta fused, fast-math ================= */
__global__ __launch_bounds__(256) void scanA(const float* __restrict__ xcin,
                                             const float* __restrict__ xdbl,
                                             const float* __restrict__ A_log,
                                             const float* __restrict__ wdt,
                                             const float* __restrict__ bdt,
                                             float* __restrict__ hxz,
                                             float* __restrict__ sdel)
{
    const int c = blockIdx.x >> 1, half = blockIdx.x & 1;
    const int b = blockIdx.y, v = blockIdx.z;
    const int d = half*256 + threadIdx.x;
    const long rowbase = (long)v*ML + (long)b*L_ + (long)c*CL_;
    const float* xcv = xcin + rowbase*DI_;
    const float* xdv = xdbl + rowbase*48;

    __shared__ float sX[CL_*48];
    for (int t = threadIdx.x; t < CL_*48; t += 256) sX[t] = xdv[t];

    float a2[16];
#pragma unroll
    for (int n = 0; n < 16; ++n)
        a2[n] = -exp2_fast(A_log[((long)v*DI_ + d)*DS_ + n] * LOG2E) * LOG2E;
    float wreg[16];
    {
        const float* wp = wdt + ((long)v*DI_ + d)*DTR_;
#pragma unroll
        for (int r = 0; r < 16; r += 4) {
            const float4 t4 = *(const float4*)(wp + r);
            wreg[r]=t4.x; wreg[r+1]=t4.y; wreg[r+2]=t4.z; wreg[r+3]=t4.w;
        }
    }
    const float bias = bdt[(long)v*DI_ + d];
    float h[16];
#pragma unroll
    for (int n = 0; n < 16; ++n) h[n] = 0.f;
    float sdsum = 0.f;
    __syncthreads();

    float xcur[8], xnxt[8];
#pragma unroll
    for (int s = 0; s < 8; ++s) xcur[s] = xcv[(long)s*DI_ + d];

    for (int g = 0; g < CL_; g += 8) {
        if (g + 8 < CL_) {
#pragma unroll
            for (int s = 0; s < 8; ++s) xnxt[s] = xcv[(long)(g+8+s)*DI_ + d];
        }
#pragma unroll
        for (int s = 0; s < 8; ++s) {
            const float* xrow = &sX[(g+s)*48];
            const float4 t0 = *(const float4*)&xrow[0];
            const float4 t1 = *(const float4*)&xrow[4];
            const float4 t2 = *(const float4*)&xrow[8];
            const float4 t3 = *(const float4*)&xrow[12];
            float acc = bias;
            acc = fmaf(t0.x,wreg[0],acc);  acc = fmaf(t0.y,wreg[1],acc);
            acc = fmaf(t0.z,wreg[2],acc);  acc = fmaf(t0.w,wreg[3],acc);
            acc = fmaf(t1.x,wreg[4],acc);  acc = fmaf(t1.y,wreg[5],acc);
            acc = fmaf(t1.z,wreg[6],acc);  acc = fmaf(t1.w,wreg[7],acc);
            acc = fmaf(t2.x,wreg[8],acc);  acc = fmaf(t2.y,wreg[9],acc);
            acc = fmaf(t2.z,wreg[10],acc); acc = fmaf(t2.w,wreg[11],acc);
            acc = fmaf(t3.x,wreg[12],acc); acc = fmaf(t3.y,wreg[13],acc);
            acc = fmaf(t3.z,wreg[14],acc); acc = fmaf(t3.w,wreg[15],acc);
            const float delta = softplus_fast(acc);
            const float tx = delta * xcur[s];
            sdsum += delta;
#pragma unroll
            for (int n4 = 0; n4 < 4; ++n4) {
                const float4 Bv = *(const float4*)&xrow[16 + n4*4];
                h[n4*4+0] = fmaf(exp2_fast(delta*a2[n4*4+0]), h[n4*4+0], tx*Bv.x);
                h[n4*4+1] = fmaf(exp2_fast(delta*a2[n4*4+1]), h[n4*4+1], tx*Bv.y);
                h[n4*4+2] = fmaf(exp2_fast(delta*a2[n4*4+2]), h[n4*4+2], tx*Bv.z);
                h[n4*4+3] = fmaf(exp2_fast(delta*a2[n4*4+3]), h[n4*4+3], tx*Bv.w);
            }
        }
#pragma unroll
        for (int s = 0; s < 8; ++s) xcur[s] = xnxt[s];
    }
    float* hb = hxz + hb_idx(v, b, c, d);
#pragma unroll
    for (int n = 0; n < 16; n += 4) {
        float4 r; r.x = h[n]; r.y = h[n+1]; r.z = h[n+2]; r.w = h[n+3];
        *(float4*)&hb[n] = r;
    }
    sdel[(((long)v*B_ + b)*NC_ + c)*DI_ + d] = sdsum;
}

__global__ __launch_bounds__(256) void scanB(const float* __restrict__ A_log,
                                             const float* __restrict__ sdel,
                                             float* __restrict__ hxz)
{
    const long lin = (long)blockIdx.x*256 + threadIdx.x;   /* 131072 = V*B*DI*DS */
    const int n = (int)(lin & 15);
    const int d = (int)((lin >> 4) & 511);
    const int b = (int)((lin >> 13) & 3);
    const int v = (int)(lin >> 15);
    const float a2 = -exp2_fast(A_log[((long)v*DI_ + d)*DS_ + n] * LOG2E) * LOG2E;
    float h = 0.f;
    long hidx = hb_idx(v, b, 0, d) + n;
    long sidx = ((long)(v*B_ + b)*NC_)*DI_ + d;
#pragma unroll
    for (int c = 0; c < NC_; ++c) {
        const float he = hxz[hidx];
        const float P  = exp2_fast(a2 * sdel[sidx]);
        hxz[hidx] = h;                 /* incoming state for chunk c */
        h = fmaf(P, h, he);
        hidx += (long)16*(2*DI_);      /* next chunk: +16 rows of 1024 */
        sidx += DI_;
    }
}

/* scanC: seeded local scan + skip + gate, fast-math; writes packed bf16 y over xc */
__global__ __launch_bounds__(256) void scanC(const float* __restrict__ xz,
                                             const float* __restrict__ xcin,
                                             const float* __restrict__ xdbl,
                                             const float* __restrict__ A_log,
                                             const float* __restrict__ wdt,
                                             const float* __restrict__ bdt,
                                             const float* __restrict__ D_skip,
                                             float* __restrict__ yout)
{
    const int c = blockIdx.x >> 1, half = blockIdx.x & 1;
    const int b = blockIdx.y, v = blockIdx.z;
    const int d = half*256 + threadIdx.x;
    const long rowbase = (long)v*ML + (long)b*L_ + (long)c*CL_;
    const float* xzv = xz   + rowbase*(2*DI_);
    const float* xcv = xcin + rowbase*DI_;
    const float* xdv = xdbl + rowbase*48;
    uint*        yv  = (uint*)yout + rowbase*DI_;

    __shared__ float sX[CL_*48];
    for (int t = threadIdx.x; t < CL_*48; t += 256) sX[t] = xdv[t];

    float a2[16];
#pragma unroll
    for (int n = 0; n < 16; ++n)
        a2[n] = -exp2_fast(A_log[((long)v*DI_ + d)*DS_ + n] * LOG2E) * LOG2E;
    float wreg[16];
    {
        const float* wp = wdt + ((long)v*DI_ + d)*DTR_;
#pragma unroll
        for (int r = 0; r < 16; r += 4) {
            const float4 t4 = *(const float4*)(wp + r);
            wreg[r]=t4.x; wreg[r+1]=t4.y; wreg[r+2]=t4.z; wreg[r+3]=t4.w;
        }
    }
    const float bias = bdt[(long)v*DI_ + d];
    const float dsk = D_skip[v*DI_ + d];
    float h[16];
    const float* hb = xz + hb_idx(v, b, c, d);
#pragma unroll
    for (int n = 0; n < 16; n += 4) {
        const float4 r = *(const float4*)&hb[n];
        h[n] = r.x; h[n+1] = r.y; h[n+2] = r.z; h[n+3] = r.w;
    }
    __syncthreads();

    float xcur[8], zcur[8], xnxt[8], znxt[8];
#pragma unroll
    for (int s = 0; s < 8; ++s) {
        xcur[s] = xcv[(long)s*DI_ + d];
        zcur[s] = xzv[(long)s*(2*DI_) + DI_ + d];
    }

    for (int g = 0; g < CL_; g += 8) {
        if (g + 8 < CL_) {
#pragma unroll
            for (int s = 0; s < 8; ++s) {
                xnxt[s] = xcv[(long)(g+8+s)*DI_ + d];
                znxt[s] = xzv[(long)(g+8+s)*(2*DI_) + DI_ + d];
            }
        }
#pragma unroll
        for (int s = 0; s < 8; ++s) {
            const float* xrow = &sX[(g+s)*48];
            const float4 t0 = *(const float4*)&xrow[0];
            const float4 t1 = *(const float4*)&xrow[4];
            const float4 t2 = *(const float4*)&xrow[8];
            const float4 t3 = *(const float4*)&xrow[12];
            float acc = bias;
            acc = fmaf(t0.x,wreg[0],acc);  acc = fmaf(t0.y,wreg[1],acc);
            acc = fmaf(t0.z,wreg[2],acc);  acc = fmaf(t0.w,wreg[3],acc);
            acc = fmaf(t1.x,wreg[4],acc);  acc = fmaf(t1.y,wreg[5],acc);
            acc = fmaf(t1.z,wreg[6],acc);  acc = fmaf(t1.w,wreg[7],acc);
            acc = fmaf(t2.x,wreg[8],acc);  acc = fmaf(t2.y,wreg[9],acc);
            acc = fmaf(t2.z,wreg[10],acc); acc = fmaf(t2.w,wreg[11],acc);
            acc = fmaf(t3.x,wreg[12],acc); acc = fmaf(t3.y,wreg[13],acc);
            acc = fmaf(t3.z,wreg[14],acc); acc = fmaf(t3.w,wreg[15],acc);
            const float delta = softplus_fast(acc);
            const float xcval = xcur[s];
            const float tx = delta * xcval;
            float ys = 0.f;
#pragma unroll
            for (int n4 = 0; n4 < 4; ++n4) {
                const float4 Bv = *(const float4*)&xrow[16 + n4*4];
                const float4 Cv = *(const float4*)&xrow[32 + n4*4];
                h[n4*4+0] = fmaf(exp2_fast(delta*a2[n4*4+0]), h[n4*4+0], tx*Bv.x);
                h[n4*4+1] = fmaf(exp2_fast(delta*a2[n4*4+1]), h[n4*4+1], tx*Bv.y);
                h[n4*4+2] = fmaf(exp2_fast(delta*a2[n4*4+2]), h[n4*4+2], tx*Bv.z);
                h[n4*4+3] = fmaf(exp2_fast(delta*a2[n4*4+3]), h[n4*4+3], tx*Bv.w);
                ys = fmaf(h[n4*4+0], Cv.x, ys);
                ys = fmaf(h[n4*4+1], Cv.y, ys);
                ys = fmaf(h[n4*4+2], Cv.z, ys);
                ys = fmaf(h[n4*4+3], Cv.w, ys);
            }
            float outv = ys + xcval * dsk;
            outv *= silu_fast(zcur[s]);
            const ushort hv = f2bf(outv);
            const ushort lv = f2bf(outv - bf2f(hv));
            yv[(long)(g+s)*DI_ + d] = (uint)hv | ((uint)lv << 16);
        }
#pragma unroll
        for (int s = 0; s < 8; ++s) { xcur[s] = xnxt[s]; zcur[s] = znxt[s]; }
    }
}

extern "C" void kernel_launch(void* const* d_in, const int* in_sizes, int n_in,
                              void* d_out, int out_size, void* d_ws, size_t ws_size,
                              hipStream_t stream)
{
    const float* x      = (const float*)d_in[0];
    const float* ln_g   = (const float*)d_in[1];
    const float* ln_b   = (const float*)d_in[2];
    const float* w_in   = (const float*)d_in[3];
    const float* conv_w = (const float*)d_in[4];
    const float* conv_b = (const float*)d_in[5];
    const float* w_x    = (const float*)d_in[6];
    const float* w_dt   = (const float*)d_in[7];
    const float* b_dt   = (const float*)d_in[8];
    const float* A_log  = (const float*)d_in[9];
    const float* D_skip = (const float*)d_in[10];
    const float* w_out  = (const float*)d_in[11];
    float* out = (float*)d_out;

    float* ws   = (float*)d_ws;
    float* xz   = ws + OFF_XZ;
    float* xc   = ws + OFF_XC;
    float* xdbl = ws + OFF_XDBL;
    float* sdel = ws + OFF_RA;      /* dead between gemm_in and w_out split */

    ushort* xlnh = (ushort*)(ws + OFF_RA);
    ushort* xlnl = xlnh + (long)V_*ML*D_;
    ushort* wih = (ushort*)(ws + OFF_XC);
    ushort* wil = wih + (long)V_*(2*DI_)*D_;
    ushort* woh = (ushort*)(ws + OFF_RA);
    ushort* wol = woh + (long)V_*D_*DI_;

    /* 1. weight split for gemm-in */
    split_w<<<dim3((V_*(2*DI_)*D_/4 + 255)/256), 256, 0, stream>>>(w_in, wih, wil, V_*(2*DI_)*D_/4);

    /* 2. LayerNorm fused with hi/lo split */
    ln_split<<<dim3(ML, V_), 256, 0, stream>>>(x, ln_g, ln_b, xlnh, xlnl);

    /* 3. xz = xln @ w_in^T via 3-term split-bf16 MFMA */
    mfma_gemm_in<<<dim3((2*DI_)/128, ML/128, V_), 256, 0, stream>>>(xlnh, xlnl, wih, wil, xz);

    /* 4. depthwise causal conv + SiLU -> xc f32 */
    conv_silu<<<dim3(ML, V_), DI_, 0, stream>>>(xz, conv_w, conv_b, xc);

    /* 5. xdbl = xc @ w_x^T, split-K=4 (partials in dead xi half of xz) + reduce */
    gemm_nt48_sk<<<dim3(ML/64, 4, V_), 256, 0, stream>>>(
        xc, w_x, xz, (long)ML*DI_, (long)48*DI_);
    reduce48<<<dim3((V_*ML*48 + 255)/256), 256, 0, stream>>>(xz, xdbl);

    /* 6. chunked parallel scan (NC=32); hbuf lives in the dead xi half of xz */
    scanA<<<dim3(NC_*2, B_, V_), 256, 0, stream>>>(xc, xdbl, A_log, w_dt, b_dt, xz, sdel);
    scanB<<<dim3((V_*B_*DI_*DS_)/256), 256, 0, stream>>>(A_log, sdel, xz);
    scanC<<<dim3(NC_*2, B_, V_), 256, 0, stream>>>(xz, xc, xdbl, A_log, w_dt, b_dt,
                                                   D_skip, xc);

    /* 7. weight split for gemm-out (RA region now dead) */
    split_w<<<dim3((V_*D_*DI_/4 + 255)/256), 256, 0, stream>>>(w_out, woh, wol, V_*D_*DI_/4);

    /* 8. out = y @ w_out^T via 3-term split-bf16 MFMA, scattered + duplicated */
    mfma_gemm_out<<<dim3(D_/128, ML/128, V_), 256, 0, stream>>>((const uint*)xc, woh, wol, out);
}